// Round 8
// baseline (1202.997 us; speedup 1.0000x reference)
//
#include <hip/hip_runtime.h>

#define N_NODES 50000
#define N_EDGES 400000
#define N_GRAPHS 64
#define EMB 64
#define H 128
#define EPS 1e-5f

typedef __attribute__((ext_vector_type(8))) short bf16x8;
typedef __attribute__((ext_vector_type(4))) float f32x4;

__device__ __forceinline__ unsigned short f2b(float f) {
    unsigned int u = __builtin_bit_cast(unsigned int, f);
    unsigned int r = (u + 0x7fff + ((u >> 16) & 1)) >> 16;  // RNE
    return (unsigned short)r;
}

// ---------------- CSR build ----------------

__global__ void count_deg_kernel(const int* __restrict__ dst, int* __restrict__ deg) {
    int rel = blockIdx.y;
    int e = blockIdx.x * 256 + threadIdx.x;
    if (e < N_EDGES) atomicAdd(&deg[rel * N_NODES + dst[rel * N_EDGES + e]], 1);
}

// 4 elems/thread, 4096/chunk -> 13 chunks; writes row_ptr AND cur
__global__ void scan_kernel(const int* __restrict__ deg, int* __restrict__ row_ptr,
                            int* __restrict__ cur) {
    int rel = blockIdx.x;
    const int* d = deg + rel * N_NODES;
    int* rp = row_ptr + rel * (N_NODES + 1);
    int* cu = cur + rel * N_NODES;
    __shared__ int sm[1024];
    __shared__ int carry;
    if (threadIdx.x == 0) carry = 0;
    __syncthreads();
    for (int base = 0; base < N_NODES; base += 4096) {
        int i0 = base + (int)threadIdx.x * 4;
        int v[4];
        int s = 0;
#pragma unroll
        for (int k = 0; k < 4; k++) { v[k] = (i0 + k < N_NODES) ? d[i0 + k] : 0; s += v[k]; }
        sm[threadIdx.x] = s;
        __syncthreads();
        for (int off = 1; off < 1024; off <<= 1) {
            int t = (threadIdx.x >= off) ? sm[threadIdx.x - off] : 0;
            __syncthreads();
            sm[threadIdx.x] += t;
            __syncthreads();
        }
        int run = carry + sm[threadIdx.x] - s;
#pragma unroll
        for (int k = 0; k < 4; k++) {
            if (i0 + k < N_NODES) { rp[i0 + k] = run; cu[i0 + k] = run; }
            run += v[k];
        }
        __syncthreads();
        if (threadIdx.x == 1023) carry += sm[1023];
        __syncthreads();
    }
    if (threadIdx.x == 0) rp[N_NODES] = carry;
}

__global__ void fill_kernel(const int* __restrict__ src, const int* __restrict__ dst,
                            int* __restrict__ cur, int* __restrict__ edge_src) {
    int rel = blockIdx.y;
    int e = blockIdx.x * 256 + threadIdx.x;
    if (e < N_EDGES) {
        int dn = dst[rel * N_EDGES + e];
        int pos = atomicAdd(&cur[rel * N_NODES + dn], 1);
        edge_src[rel * N_EDGES + pos] = src[rel * N_EDGES + e];
    }
}

// ---------------- Degree counting-sort (node permutation, shared by all layers) ----------------

__global__ void hist_kernel(const int* __restrict__ deg, int* __restrict__ dhist) {
    int i = blockIdx.x * 256 + threadIdx.x;
    if (i < 3 * N_NODES) {
        int rel = i / N_NODES;
        int b = min(deg[i], 255);
        atomicAdd(&dhist[rel * 256 + b], 1);
    }
}

__global__ void bucket_scan_kernel(const int* __restrict__ dhist, int* __restrict__ dcur) {
    int rel = blockIdx.x, t = threadIdx.x;
    __shared__ int sm[256];
    int h = dhist[rel * 256 + t];
    sm[t] = h;
    __syncthreads();
    for (int off = 1; off < 256; off <<= 1) {
        int v = (t >= off) ? sm[t - off] : 0;
        __syncthreads();
        sm[t] += v;
        __syncthreads();
    }
    dcur[rel * 256 + t] = sm[t] - h;  // exclusive base
}

__global__ void place_kernel(const int* __restrict__ deg, int* __restrict__ dcur,
                             int* __restrict__ perm) {
    int i = blockIdx.x * 256 + threadIdx.x;
    if (i < 3 * N_NODES) {
        int rel = i / N_NODES, n = i - rel * N_NODES;
        int b = min(deg[i], 255);
        int pos = atomicAdd(&dcur[rel * 256 + b], 1);
        perm[rel * N_NODES + pos] = n;
    }
}

// ---------------- Embedding gather -> bf16 x0 ----------------

__global__ void embed_kernel(const int* __restrict__ h_idx, const int* __restrict__ p_idx,
                             const int* __restrict__ hp_idx,
                             const float* __restrict__ emb_h, const float* __restrict__ emb_p,
                             const float* __restrict__ emb_hp,
                             unsigned short* __restrict__ x) {
    int rel = blockIdx.y;
    int i = blockIdx.x * 256 + threadIdx.x;  // 8-col units
    if (i >= N_NODES * EMB / 8) return;
    int n = i / (EMB / 8), c8 = (i % (EMB / 8)) * 8;
    const int* idx = rel == 0 ? h_idx : (rel == 1 ? p_idx : hp_idx);
    const float* emb = rel == 0 ? emb_h : (rel == 1 ? emb_p : emb_hp);
    const float* e = emb + (size_t)idx[n] * EMB + c8;
    unsigned short o[8];
#pragma unroll
    for (int j = 0; j < 8; j++) o[j] = f2b(e[j]);
    *(uint4*)&x[(size_t)rel * N_NODES * EMB + (size_t)n * EMB + c8] = *(uint4*)o;
}

// ---------------- Neighbor mean aggregation (degree-sorted nodes) ----------------
// Output nmean has ld = DIN. deg==0 -> exact 0 (reference semantics).

template <int DIN, bool FOLD>
__global__ __launch_bounds__(256) void aggregate_kernel(
        const unsigned short* __restrict__ x, int ldx,
        const int* __restrict__ row_ptr, const int* __restrict__ edge_src,
        const int* __restrict__ perm,
        const float* __restrict__ st,
        unsigned short* __restrict__ nmean) {
    const int TPN = DIN / 8;
    int rel = blockIdx.y;
    int slot = blockIdx.x * (256 / TPN) + threadIdx.x / TPN;
    int c8 = (threadIdx.x % TPN) * 8;
    if (slot >= N_NODES) return;
    int node = perm[rel * N_NODES + slot];
    const int* rp = row_ptr + rel * (N_NODES + 1);
    const int* es = edge_src + rel * N_EDGES;
    const unsigned short* xr = x + (size_t)rel * N_NODES * ldx;
    int s0 = rp[node], s1 = rp[node + 1];
    float acc[8];
#pragma unroll
    for (int j = 0; j < 8; j++) acc[j] = 0.f;

#define ACCUM(V)                                                                      \
    {                                                                                 \
        unsigned int w[4] = {(V).x, (V).y, (V).z, (V).w};                             \
        _Pragma("unroll") for (int j = 0; j < 4; j++) {                               \
            acc[2 * j] += __builtin_bit_cast(float, w[j] << 16);                      \
            acc[2 * j + 1] += __builtin_bit_cast(float, w[j] & 0xffff0000u);          \
        }                                                                             \
    }

    int e = s0;
    for (; e + 4 <= s1; e += 4) {
        int i0 = es[e], i1 = es[e + 1], i2 = es[e + 2], i3 = es[e + 3];
        uint4 v0 = *(const uint4*)&xr[(size_t)i0 * ldx + c8];
        uint4 v1 = *(const uint4*)&xr[(size_t)i1 * ldx + c8];
        uint4 v2 = *(const uint4*)&xr[(size_t)i2 * ldx + c8];
        uint4 v3 = *(const uint4*)&xr[(size_t)i3 * ldx + c8];
        ACCUM(v0) ACCUM(v1) ACCUM(v2) ACCUM(v3)
    }
    for (; e < s1; e++) {
        uint4 v0 = *(const uint4*)&xr[(size_t)es[e] * ldx + c8];
        ACCUM(v0)
    }
#undef ACCUM
    int deg = s1 - s0;
    float inv = 1.f / (float)max(deg, 1);
    unsigned short o[8];
#pragma unroll
    for (int j = 0; j < 8; j++) {
        float m = acc[j] * inv;
        if (FOLD) {
            float s = st[rel * 2 * H + c8 + j];
            float t = st[rel * 2 * H + H + c8 + j];
            m = s * m + t;
        }
        o[j] = (deg > 0) ? f2b(m) : (unsigned short)0;
    }
    *(uint4*)&nmean[((size_t)rel * N_NODES + node) * DIN + c8] = *(uint4*)o;
}

// ---- MFMA GEMM (LDS-staged): hp = PReLU([x | nmean] @ Wbt^T + bias);
//      fp32 col stats; per-graph readout sums fused into epilogue. ----

template <int KX>
__global__ __launch_bounds__(256) void gemm_kernel(
        const unsigned short* __restrict__ x,      // [rel][N][KX] bf16 self input
        const unsigned short* __restrict__ nmean,  // [rel][N][KX] bf16
        const unsigned short* __restrict__ Wbt,    // [rel][H cols][2*KX] bf16
        const float* __restrict__ bias,            // [rel][H]
        const float* __restrict__ alpha,           // [rel][H]
        unsigned short* __restrict__ out,          // [rel][N][H] bf16 (pre-BN)
        float* __restrict__ stats,
        const int* __restrict__ seg_all,           // [rel][N] sorted graph ids
        float* __restrict__ gout,                  // [G][3][4][H] sum accumulator
        int layer) {
    const int KTOT = 2 * KX;
    int rel = blockIdx.y;
    int row0 = blockIdx.x * 128;
    const unsigned short* xr = x + (size_t)rel * N_NODES * KX;
    const unsigned short* nm = nmean + (size_t)rel * N_NODES * KX;
    const unsigned short* W = Wbt + (size_t)rel * H * KTOT;
    unsigned short* o = out + (size_t)rel * N_NODES * H;

    __shared__ __align__(16) short At[128][40];
    __shared__ __align__(16) short Bt[128][40];

    int tid = threadIdx.x;
    int lane = tid & 63;
    int wave = tid >> 6;
    int wr = wave >> 1, wc = wave & 1;
    int l15 = lane & 15;
    int koff = (lane >> 4) * 8;

    f32x4 acc[4][4];
#pragma unroll
    for (int m = 0; m < 4; m++)
#pragma unroll
        for (int n = 0; n < 4; n++) acc[m][n] = (f32x4){0.f, 0.f, 0.f, 0.f};

    int seg = tid & 3;
    int rloc = tid >> 2;

    for (int kc = 0; kc < KTOT; kc += 32) {
        const unsigned short* Asrc;
        int kb;
        if (kc < KX) { Asrc = xr; kb = kc; }
        else         { Asrc = nm; kb = kc - KX; }
#pragma unroll
        for (int i = 0; i < 2; i++) {
            int r = i * 64 + rloc;
            int gr = row0 + r;
            uint4 v = make_uint4(0u, 0u, 0u, 0u);
            if (gr < N_NODES) v = *(const uint4*)&Asrc[(size_t)gr * KX + kb + seg * 8];
            *(uint4*)&At[r][seg * 8] = v;
        }
#pragma unroll
        for (int i = 0; i < 2; i++) {
            int c = i * 64 + rloc;
            *(uint4*)&Bt[c][seg * 8] = *(const uint4*)&W[(size_t)c * KTOT + kc + seg * 8];
        }
        __syncthreads();
        bf16x8 a[4], b[4];
#pragma unroll
        for (int m = 0; m < 4; m++) a[m] = *(const bf16x8*)&At[wr * 64 + m * 16 + l15][koff];
#pragma unroll
        for (int n = 0; n < 4; n++) b[n] = *(const bf16x8*)&Bt[wc * 64 + n * 16 + l15][koff];
#pragma unroll
        for (int m = 0; m < 4; m++)
#pragma unroll
            for (int n = 0; n < 4; n++)
                acc[m][n] = __builtin_amdgcn_mfma_f32_16x16x32_bf16(a[m], b[n], acc[m][n], 0, 0, 0);
        __syncthreads();
    }

    // epilogue: bias + PReLU, bf16 store, fp32 column stats, per-graph run sums
    float bs[4], as_[4];
#pragma unroll
    for (int n = 0; n < 4; n++) {
        int col = wc * 64 + n * 16 + l15;
        bs[n] = bias[rel * H + col];
        as_[n] = alpha[rel * H + col];
    }
    const int* sg = seg_all + rel * N_NODES;
    float csum[4] = {0.f, 0.f, 0.f, 0.f}, cssq[4] = {0.f, 0.f, 0.f, 0.f};
    int curg = -1;
    float run[4] = {0.f, 0.f, 0.f, 0.f};
    int rbase = row0 + wr * 64 + (lane >> 4) * 4;
#pragma unroll
    for (int m = 0; m < 4; m++) {
#pragma unroll
        for (int j = 0; j < 4; j++) {
            int r = rbase + m * 16 + j;
            if (r >= N_NODES) continue;
            int g = sg[r];
            if (g != curg) {
                if (curg >= 0) {
                    float* ob = gout + (size_t)curg * (3 * 4 * H) + rel * (4 * H) + layer * H + wc * 64 + l15;
#pragma unroll
                    for (int n = 0; n < 4; n++) { atomicAdd(ob + n * 16, run[n]); run[n] = 0.f; }
                }
                curg = g;
            }
#pragma unroll
            for (int n = 0; n < 4; n++) {
                float v = acc[m][n][j] + bs[n];
                v = v > 0.f ? v : as_[n] * v;
                o[(size_t)r * H + wc * 64 + n * 16 + l15] = f2b(v);
                csum[n] += v;
                cssq[n] += v * v;
                run[n] += v;
            }
        }
    }
    if (curg >= 0) {
        float* ob = gout + (size_t)curg * (3 * 4 * H) + rel * (4 * H) + layer * H + wc * 64 + l15;
#pragma unroll
        for (int n = 0; n < 4; n++) atomicAdd(ob + n * 16, run[n]);
    }
    __syncthreads();
    float* smS = (float*)&At[0][0];   // 128 cols x 8 contributors = 4 KB
    float* smQ = (float*)&Bt[0][0];
    int contrib = wr * 4 + (lane >> 4);
#pragma unroll
    for (int n = 0; n < 4; n++) {
        int col = wc * 64 + n * 16 + l15;
        smS[col * 8 + contrib] = csum[n];
        smQ[col * 8 + contrib] = cssq[n];
    }
    __syncthreads();
    if (tid < 128) {
        float s = 0.f, q = 0.f;
#pragma unroll
        for (int i = 0; i < 8; i++) { s += smS[tid * 8 + i]; q += smQ[tid * 8 + i]; }
        atomicAdd(&stats[rel * 256 + tid], s);
        atomicAdd(&stats[rel * 256 + 128 + tid], q);
    }
}

// ---------------- BN stats -> affine (s,t); self-zero stats for next layer ----------------

__global__ void finalize_kernel(float* __restrict__ stats,
                                const float* __restrict__ gamma, const float* __restrict__ beta,
                                float* __restrict__ st) {
    int rel = blockIdx.x, c = threadIdx.x;
    const float invN = 1.f / N_NODES;
    float mu = stats[rel * 256 + c] * invN;
    float var = stats[rel * 256 + 128 + c] * invN - mu * mu;
    float s = gamma[rel * H + c] * rsqrtf(var + EPS);
    st[rel * 2 * H + c] = s;
    st[rel * 2 * H + H + c] = beta[rel * H + c] - mu * s;
    stats[rel * 256 + c] = 0.f;
    stats[rel * 256 + 128 + c] = 0.f;
}

// ---------------- Weight prep ----------------

__global__ void prep1_kernel(const float* __restrict__ Wself, const float* __restrict__ Wneigh,
                             unsigned short* __restrict__ Wbt) {
    int idx = blockIdx.x * 256 + threadIdx.x;
    if (idx >= 3 * H * 128) return;
    int rel = idx / (H * 128), rem = idx % (H * 128);
    int c = rem / 128, k = rem % 128;
    float v = (k < 64) ? Wself[((size_t)rel * 64 + k) * H + c]
                       : Wneigh[((size_t)rel * 64 + (k - 64)) * H + c];
    Wbt[idx] = f2b(v);
}

// merged: blocks 0..383 -> W fold/convert; blocks 384..386 -> bias fold
__global__ void prep_kernel(const float* __restrict__ Wself, const float* __restrict__ Wneigh,
                            const float* __restrict__ b, const float* __restrict__ st,
                            unsigned short* __restrict__ Wbt, float* __restrict__ biasp) {
    if (blockIdx.x < 384) {
        int idx = blockIdx.x * 256 + threadIdx.x;
        int rel = idx / (H * 256), rem = idx % (H * 256);
        int c = rem / 256, k = rem % 256;
        float v;
        if (k < 128) v = st[rel * 2 * H + k] * Wself[((size_t)rel * H + k) * H + c];
        else         v = Wneigh[((size_t)rel * H + (k - 128)) * H + c];
        Wbt[idx] = f2b(v);
    } else if (threadIdx.x < H) {
        int rel = blockIdx.x - 384, c = threadIdx.x;
        const float* t = st + rel * 2 * H + H;
        float s = b[rel * H + c];
        for (int k = 0; k < H; k++) s += t[k] * Wself[((size_t)rel * H + k) * H + c];
        biasp[rel * H + c] = s;
    }
}

// ---------------- Final: mean + BN affine ----------------

__global__ void scale_out_kernel(float* __restrict__ out, const int* __restrict__ seg,
                                 const float* __restrict__ st_all) {
    int i = blockIdx.x * 256 + threadIdx.x;
    if (i >= N_GRAPHS * 3 * 4 * H) return;
    int g = i / (3 * 4 * H), k = i % (3 * 4 * H);
    int rel = k / (4 * H), rem = k % (4 * H), layer = rem / H, c = rem % H;
    const int* sg = seg + rel * N_NODES;
    int lo = 0, hi = N_NODES;
    while (lo < hi) { int m = (lo + hi) >> 1; if (sg[m] < g) lo = m + 1; else hi = m; }
    int start = lo;
    hi = N_NODES;
    while (lo < hi) { int m = (lo + hi) >> 1; if (sg[m] <= g) lo = m + 1; else hi = m; }
    int cnt = lo - start;
    float mean = out[i] / (float)max(cnt, 1);
    const float* st = st_all + ((size_t)layer * 3 + rel) * 2 * H;
    out[i] = st[c] * mean + st[H + c];
}

// ---------------- Orchestration ----------------

extern "C" void kernel_launch(void* const* d_in, const int* in_sizes, int n_in,
                              void* d_out, int out_size, void* d_ws, size_t ws_size,
                              hipStream_t stream) {
    const int* h_idx = (const int*)d_in[0];
    const int* p_idx = (const int*)d_in[1];
    const int* hp_idx = (const int*)d_in[2];
    const int* src = (const int*)d_in[3];
    const int* dst = (const int*)d_in[4];
    const int* seg = (const int*)d_in[5];
    const float* emb_h = (const float*)d_in[6];
    const float* emb_p = (const float*)d_in[7];
    const float* emb_hp = (const float*)d_in[8];
    const float* W1_self = (const float*)d_in[9];
    const float* W1_neigh = (const float*)d_in[10];
    const float* b1 = (const float*)d_in[11];
    const float* a1 = (const float*)d_in[12];
    const float* gamma1 = (const float*)d_in[13];
    const float* beta1 = (const float*)d_in[14];
    const float* W_self = (const float*)d_in[15];
    const float* W_neigh = (const float*)d_in[16];
    const float* b = (const float*)d_in[17];
    const float* a = (const float*)d_in[18];
    const float* gamma = (const float*)d_in[19];
    const float* beta = (const float*)d_in[20];
    float* out = (float*)d_out;

    // workspace
    char* p = (char*)d_ws;
    unsigned short* x0 = (unsigned short*)p; p += (size_t)3 * N_NODES * EMB * 2;   // 19.2 MB
    unsigned short* hpA = (unsigned short*)p; p += (size_t)3 * N_NODES * H * 2;    // 38.4 MB
    unsigned short* hpB = (unsigned short*)p; p += (size_t)3 * N_NODES * H * 2;    // 38.4 MB
    unsigned short* Wbt1 = (unsigned short*)p; p += (size_t)3 * H * 128 * 2;
    unsigned short* Wbt = (unsigned short*)p; p += (size_t)3 * H * 256 * 2;
    float* biasp = (float*)p; p += 3 * H * sizeof(float);
    float* st_all = (float*)p; p += 4 * 3 * 2 * H * sizeof(float);
    float* stats = (float*)p; p += 3 * 256 * sizeof(float);
    int* deg = (int*)p; p += (size_t)3 * N_NODES * 4;
    int* row_ptr = (int*)p; p += (size_t)3 * (N_NODES + 1) * 4;
    int* cur = (int*)p; p += (size_t)3 * N_NODES * 4;
    int* edge_src = (int*)p; p += (size_t)3 * N_EDGES * 4;
    int* dhist = (int*)p; p += 3 * 256 * 4;
    int* dcur = (int*)p; p += 3 * 256 * 4;
    int* perm = (int*)p; p += (size_t)3 * N_NODES * 4;

    hipMemsetAsync(out, 0, (size_t)N_GRAPHS * 3 * 4 * H * sizeof(float), stream);
    hipMemsetAsync(stats, 0, 3 * 256 * 4, stream);

    // CSR build
    hipMemsetAsync(deg, 0, (size_t)3 * N_NODES * 4, stream);
    hipMemsetAsync(dhist, 0, 3 * 256 * 4, stream);
    dim3 eb((N_EDGES + 255) / 256, 3);
    count_deg_kernel<<<eb, 256, 0, stream>>>(dst, deg);
    scan_kernel<<<3, 1024, 0, stream>>>(deg, row_ptr, cur);
    fill_kernel<<<eb, 256, 0, stream>>>(src, dst, cur, edge_src);

    // degree counting-sort -> perm (shared by all 4 layers)
    hist_kernel<<<(3 * N_NODES + 255) / 256, 256, 0, stream>>>(deg, dhist);
    bucket_scan_kernel<<<3, 256, 0, stream>>>(dhist, dcur);
    place_kernel<<<(3 * N_NODES + 255) / 256, 256, 0, stream>>>(deg, dcur, perm);

    embed_kernel<<<dim3((N_NODES * EMB / 8 + 255) / 256, 3), 256, 0, stream>>>(
        h_idx, p_idx, hp_idx, emb_h, emb_p, emb_hp, x0);
    prep1_kernel<<<(3 * H * 128 + 255) / 256, 256, 0, stream>>>(W1_self, W1_neigh, Wbt1);

    dim3 gemm_grid((N_NODES + 127) / 128, 3);

    // ---- layer 1 (K = 64; nmean ld=64 in hpB; out hpA) ----
    aggregate_kernel<64, false><<<dim3((N_NODES + 31) / 32, 3), 256, 0, stream>>>(
        x0, EMB, row_ptr, edge_src, perm, nullptr, hpB);
    gemm_kernel<64><<<gemm_grid, 256, 0, stream>>>(
        x0, hpB, Wbt1, b1, a1, hpA, stats, seg, out, 0);
    finalize_kernel<<<3, H, 0, stream>>>(stats, gamma1, beta1, st_all);

    // ---- layers 2-4 (K = 128; out aliases nmean) ----
    unsigned short* xin = hpA;
    unsigned short* xout = hpB;
    for (int l = 0; l < 3; l++) {
        const float* st_prev = st_all + (size_t)l * 3 * 2 * H;
        prep_kernel<<<387, 256, 0, stream>>>(
            W_self + (size_t)l * 3 * H * H, W_neigh + (size_t)l * 3 * H * H,
            b + (size_t)l * 3 * H, st_prev, Wbt, biasp);
        aggregate_kernel<128, true><<<dim3((N_NODES + 15) / 16, 3), 256, 0, stream>>>(
            xin, H, row_ptr, edge_src, perm, st_prev, xout);
        gemm_kernel<128><<<gemm_grid, 256, 0, stream>>>(
            xin, xout, Wbt, biasp, a + (size_t)l * 3 * H, xout, stats, seg, out, l + 1);
        finalize_kernel<<<3, H, 0, stream>>>(
            stats, gamma + (size_t)l * 3 * H, beta + (size_t)l * 3 * H,
            st_all + (size_t)(l + 1) * 3 * 2 * H);
        unsigned short* t = xin; xin = xout; xout = t;
    }

    scale_out_kernel<<<(N_GRAPHS * 3 * 4 * H + 255) / 256, 256, 0, stream>>>(out, seg, st_all);
}

// Round 9
// 780.670 us; speedup vs baseline: 1.5410x; 1.5410x over previous
//
#include <hip/hip_runtime.h>

#define N_NODES 50000
#define N_EDGES 400000
#define N_GRAPHS 64
#define EMB 64
#define H 128
#define EPS 1e-5f

typedef __attribute__((ext_vector_type(8))) short bf16x8;
typedef __attribute__((ext_vector_type(4))) float f32x4;

__device__ __forceinline__ unsigned short f2b(float f) {
    unsigned int u = __builtin_bit_cast(unsigned int, f);
    unsigned int r = (u + 0x7fff + ((u >> 16) & 1)) >> 16;  // RNE
    return (unsigned short)r;
}

// ---------------- CSR build ----------------

__global__ void count_deg_kernel(const int* __restrict__ dst, int* __restrict__ deg) {
    int rel = blockIdx.y;
    int e = blockIdx.x * 256 + threadIdx.x;
    if (e < N_EDGES) atomicAdd(&deg[rel * N_NODES + dst[rel * N_EDGES + e]], 1);
}

// 4 elems/thread, 4096/chunk -> 13 chunks; writes row_ptr AND cur
__global__ void scan_kernel(const int* __restrict__ deg, int* __restrict__ row_ptr,
                            int* __restrict__ cur) {
    int rel = blockIdx.x;
    const int* d = deg + rel * N_NODES;
    int* rp = row_ptr + rel * (N_NODES + 1);
    int* cu = cur + rel * N_NODES;
    __shared__ int sm[1024];
    __shared__ int carry;
    if (threadIdx.x == 0) carry = 0;
    __syncthreads();
    for (int base = 0; base < N_NODES; base += 4096) {
        int i0 = base + (int)threadIdx.x * 4;
        int v[4];
        int s = 0;
#pragma unroll
        for (int k = 0; k < 4; k++) { v[k] = (i0 + k < N_NODES) ? d[i0 + k] : 0; s += v[k]; }
        sm[threadIdx.x] = s;
        __syncthreads();
        for (int off = 1; off < 1024; off <<= 1) {
            int t = (threadIdx.x >= off) ? sm[threadIdx.x - off] : 0;
            __syncthreads();
            sm[threadIdx.x] += t;
            __syncthreads();
        }
        int run = carry + sm[threadIdx.x] - s;
#pragma unroll
        for (int k = 0; k < 4; k++) {
            if (i0 + k < N_NODES) { rp[i0 + k] = run; cu[i0 + k] = run; }
            run += v[k];
        }
        __syncthreads();
        if (threadIdx.x == 1023) carry += sm[1023];
        __syncthreads();
    }
    if (threadIdx.x == 0) rp[N_NODES] = carry;
}

__global__ void fill_kernel(const int* __restrict__ src, const int* __restrict__ dst,
                            int* __restrict__ cur, int* __restrict__ edge_src) {
    int rel = blockIdx.y;
    int e = blockIdx.x * 256 + threadIdx.x;
    if (e < N_EDGES) {
        int dn = dst[rel * N_EDGES + e];
        int pos = atomicAdd(&cur[rel * N_NODES + dn], 1);
        edge_src[rel * N_EDGES + pos] = src[rel * N_EDGES + e];
    }
}

// ---------------- Embedding gather -> bf16 x0 ----------------

__global__ void embed_kernel(const int* __restrict__ h_idx, const int* __restrict__ p_idx,
                             const int* __restrict__ hp_idx,
                             const float* __restrict__ emb_h, const float* __restrict__ emb_p,
                             const float* __restrict__ emb_hp,
                             unsigned short* __restrict__ x) {
    int rel = blockIdx.y;
    int i = blockIdx.x * 256 + threadIdx.x;  // 8-col units
    if (i >= N_NODES * EMB / 8) return;
    int n = i / (EMB / 8), c8 = (i % (EMB / 8)) * 8;
    const int* idx = rel == 0 ? h_idx : (rel == 1 ? p_idx : hp_idx);
    const float* emb = rel == 0 ? emb_h : (rel == 1 ? emb_p : emb_hp);
    const float* e = emb + (size_t)idx[n] * EMB + c8;
    unsigned short o[8];
#pragma unroll
    for (int j = 0; j < 8; j++) o[j] = f2b(e[j]);
    *(uint4*)&x[(size_t)rel * N_NODES * EMB + (size_t)n * EMB + c8] = *(uint4*)o;
}

// bf16 copies of the tiny emb tables (for cache-resident layer-1 gather)
__global__ void embbf_kernel(const float* __restrict__ emb_h, const float* __restrict__ emb_p,
                             const float* __restrict__ emb_hp,
                             unsigned short* __restrict__ emb_bf) {
    int rel = blockIdx.y;
    int i = blockIdx.x * 256 + threadIdx.x;  // 8-elem units over 257*64/8
    if (i >= 257 * EMB / 8) return;
    const float* emb = rel == 0 ? emb_h : (rel == 1 ? emb_p : emb_hp);
    const float* e = emb + (size_t)i * 8;
    unsigned short o[8];
#pragma unroll
    for (int j = 0; j < 8; j++) o[j] = f2b(e[j]);
    *(uint4*)&emb_bf[(size_t)rel * 257 * EMB + (size_t)i * 8] = *(uint4*)o;
}

// ---------------- Layer-1 aggregation via emb tables (cache-resident) ----------------
// nmean row = mean over edges of emb_bf[rel][idx[src]]; ld = 64. deg==0 -> 0.

__global__ __launch_bounds__(256) void aggregate1_kernel(
        const int* __restrict__ h_idx, const int* __restrict__ p_idx,
        const int* __restrict__ hp_idx,
        const unsigned short* __restrict__ emb_bf,   // [3][257][64]
        const int* __restrict__ row_ptr, const int* __restrict__ edge_src,
        unsigned short* __restrict__ nmean) {
    const int TPN = 8;
    int rel = blockIdx.y;
    int node = blockIdx.x * 32 + threadIdx.x / TPN;
    int c8 = (threadIdx.x % TPN) * 8;
    if (node >= N_NODES) return;
    const int* idxarr = rel == 0 ? h_idx : (rel == 1 ? p_idx : hp_idx);
    const unsigned short* emb = emb_bf + (size_t)rel * 257 * EMB;
    const int* rp = row_ptr + rel * (N_NODES + 1);
    const int* es = edge_src + rel * N_EDGES;
    int s0 = rp[node], s1 = rp[node + 1];
    float acc[8];
#pragma unroll
    for (int j = 0; j < 8; j++) acc[j] = 0.f;

#define ACCUM(V)                                                                      \
    {                                                                                 \
        unsigned int w[4] = {(V).x, (V).y, (V).z, (V).w};                             \
        _Pragma("unroll") for (int j = 0; j < 4; j++) {                               \
            acc[2 * j] += __builtin_bit_cast(float, w[j] << 16);                      \
            acc[2 * j + 1] += __builtin_bit_cast(float, w[j] & 0xffff0000u);          \
        }                                                                             \
    }

    int e = s0;
    for (; e + 4 <= s1; e += 4) {
        int i0 = idxarr[es[e]], i1 = idxarr[es[e + 1]];
        int i2 = idxarr[es[e + 2]], i3 = idxarr[es[e + 3]];
        uint4 v0 = *(const uint4*)&emb[(size_t)i0 * EMB + c8];
        uint4 v1 = *(const uint4*)&emb[(size_t)i1 * EMB + c8];
        uint4 v2 = *(const uint4*)&emb[(size_t)i2 * EMB + c8];
        uint4 v3 = *(const uint4*)&emb[(size_t)i3 * EMB + c8];
        ACCUM(v0) ACCUM(v1) ACCUM(v2) ACCUM(v3)
    }
    for (; e < s1; e++) {
        uint4 v0 = *(const uint4*)&emb[(size_t)idxarr[es[e]] * EMB + c8];
        ACCUM(v0)
    }
    int deg = s1 - s0;
    float inv = 1.f / (float)max(deg, 1);
    unsigned short o[8];
#pragma unroll
    for (int j = 0; j < 8; j++)
        o[j] = (deg > 0) ? f2b(acc[j] * inv) : (unsigned short)0;
    *(uint4*)&nmean[((size_t)rel * N_NODES + node) * EMB + c8] = *(uint4*)o;
}

// ---------------- Layers 2-4 aggregation (bf16 gather, BN-affine fold) ----------------

template <int DIN, bool FOLD>
__global__ __launch_bounds__(256) void aggregate_kernel(
        const unsigned short* __restrict__ x, int ldx,
        const int* __restrict__ row_ptr, const int* __restrict__ edge_src,
        const float* __restrict__ st,
        unsigned short* __restrict__ nmean) {
    const int TPN = DIN / 8;
    int rel = blockIdx.y;
    int node = blockIdx.x * (256 / TPN) + threadIdx.x / TPN;
    int c8 = (threadIdx.x % TPN) * 8;
    if (node >= N_NODES) return;
    const int* rp = row_ptr + rel * (N_NODES + 1);
    const int* es = edge_src + rel * N_EDGES;
    const unsigned short* xr = x + (size_t)rel * N_NODES * ldx;
    int s0 = rp[node], s1 = rp[node + 1];
    float acc[8];
#pragma unroll
    for (int j = 0; j < 8; j++) acc[j] = 0.f;

    int e = s0;
    for (; e + 4 <= s1; e += 4) {
        int i0 = es[e], i1 = es[e + 1], i2 = es[e + 2], i3 = es[e + 3];
        uint4 v0 = *(const uint4*)&xr[(size_t)i0 * ldx + c8];
        uint4 v1 = *(const uint4*)&xr[(size_t)i1 * ldx + c8];
        uint4 v2 = *(const uint4*)&xr[(size_t)i2 * ldx + c8];
        uint4 v3 = *(const uint4*)&xr[(size_t)i3 * ldx + c8];
        ACCUM(v0) ACCUM(v1) ACCUM(v2) ACCUM(v3)
    }
    for (; e < s1; e++) {
        uint4 v0 = *(const uint4*)&xr[(size_t)es[e] * ldx + c8];
        ACCUM(v0)
    }
#undef ACCUM
    int deg = s1 - s0;
    float inv = 1.f / (float)max(deg, 1);
    unsigned short o[8];
#pragma unroll
    for (int j = 0; j < 8; j++) {
        float m = acc[j] * inv;
        if (FOLD) {
            float s = st[rel * 2 * H + c8 + j];
            float t = st[rel * 2 * H + H + c8 + j];
            m = s * m + t;
        }
        o[j] = (deg > 0) ? f2b(m) : (unsigned short)0;
    }
    *(uint4*)&nmean[((size_t)rel * N_NODES + node) * DIN + c8] = *(uint4*)o;
}

// ---- MFMA GEMM (double-buffered LDS, 1 barrier/chunk):
//      hp = PReLU([x | nmean] @ Wbt^T + bias); fp32 col stats;
//      per-graph readout sums fused into epilogue. ----

template <int KX>
__global__ __launch_bounds__(256) void gemm_kernel(
        const unsigned short* __restrict__ x,      // [rel][N][KX] bf16 self input
        const unsigned short* __restrict__ nmean,  // [rel][N][KX] bf16
        const unsigned short* __restrict__ Wbt,    // [rel][H cols][2*KX] bf16
        const float* __restrict__ bias,            // [rel][H]
        const float* __restrict__ alpha,           // [rel][H]
        unsigned short* __restrict__ out,          // [rel][N][H] bf16 (pre-BN)
        float* __restrict__ stats,
        const int* __restrict__ seg_all,           // [rel][N] sorted graph ids
        float* __restrict__ gout,                  // [G][3][4][H] sum accumulator
        int layer) {
    const int KTOT = 2 * KX;
    const int NCH = KTOT / 32;
    int rel = blockIdx.y;
    int row0 = blockIdx.x * 128;
    const unsigned short* xr = x + (size_t)rel * N_NODES * KX;
    const unsigned short* nm = nmean + (size_t)rel * N_NODES * KX;
    const unsigned short* W = Wbt + (size_t)rel * H * KTOT;
    unsigned short* o = out + (size_t)rel * N_NODES * H;

    __shared__ __align__(16) short At[2][128][40];
    __shared__ __align__(16) short Bt[2][128][40];

    int tid = threadIdx.x;
    int lane = tid & 63;
    int wave = tid >> 6;
    int wr = wave >> 1, wc = wave & 1;
    int l15 = lane & 15;
    int koff = (lane >> 4) * 8;

    int seg = tid & 3;
    int rloc = tid >> 2;
    int gr0 = row0 + rloc;            // rows this thread stages
    int gr1 = row0 + 64 + rloc;

    f32x4 acc[4][4];
#pragma unroll
    for (int m = 0; m < 4; m++)
#pragma unroll
        for (int n = 0; n < 4; n++) acc[m][n] = (f32x4){0.f, 0.f, 0.f, 0.f};

    // chunk load helper (into regs)
    uint4 va0, va1, vb0, vb1;
#define LOADCH(CH)                                                                    \
    {                                                                                 \
        int kc = (CH) * 32;                                                           \
        const unsigned short* Asrc = (kc < KX) ? xr : nm;                             \
        int kb = (kc < KX) ? kc : kc - KX;                                            \
        va0 = make_uint4(0u, 0u, 0u, 0u);                                             \
        va1 = make_uint4(0u, 0u, 0u, 0u);                                             \
        if (gr0 < N_NODES) va0 = *(const uint4*)&Asrc[(size_t)gr0 * KX + kb + seg * 8]; \
        if (gr1 < N_NODES) va1 = *(const uint4*)&Asrc[(size_t)gr1 * KX + kb + seg * 8]; \
        vb0 = *(const uint4*)&W[(size_t)rloc * KTOT + kc + seg * 8];                  \
        vb1 = *(const uint4*)&W[(size_t)(64 + rloc) * KTOT + kc + seg * 8];           \
    }
#define STORECH(BUF)                                                                  \
    {                                                                                 \
        *(uint4*)&At[BUF][rloc][seg * 8] = va0;                                       \
        *(uint4*)&At[BUF][64 + rloc][seg * 8] = va1;                                  \
        *(uint4*)&Bt[BUF][rloc][seg * 8] = vb0;                                       \
        *(uint4*)&Bt[BUF][64 + rloc][seg * 8] = vb1;                                  \
    }

    LOADCH(0)
    STORECH(0)
    __syncthreads();

    for (int ch = 0; ch < NCH; ch++) {
        int cur = ch & 1;
        if (ch + 1 < NCH) LOADCH(ch + 1)        // issue next chunk's global loads early
        bf16x8 a[4], b[4];
#pragma unroll
        for (int m = 0; m < 4; m++) a[m] = *(const bf16x8*)&At[cur][wr * 64 + m * 16 + l15][koff];
#pragma unroll
        for (int n = 0; n < 4; n++) b[n] = *(const bf16x8*)&Bt[cur][wc * 64 + n * 16 + l15][koff];
#pragma unroll
        for (int m = 0; m < 4; m++)
#pragma unroll
            for (int n = 0; n < 4; n++)
                acc[m][n] = __builtin_amdgcn_mfma_f32_16x16x32_bf16(a[m], b[n], acc[m][n], 0, 0, 0);
        if (ch + 1 < NCH) {
            STORECH(cur ^ 1)
            __syncthreads();
        }
    }
#undef LOADCH
#undef STORECH

    // epilogue: bias + PReLU, bf16 store, fp32 column stats, per-graph run sums
    float bs[4], as_[4];
#pragma unroll
    for (int n = 0; n < 4; n++) {
        int col = wc * 64 + n * 16 + l15;
        bs[n] = bias[rel * H + col];
        as_[n] = alpha[rel * H + col];
    }
    const int* sg = seg_all + rel * N_NODES;
    float csum[4] = {0.f, 0.f, 0.f, 0.f}, cssq[4] = {0.f, 0.f, 0.f, 0.f};
    int curg = -1;
    float run[4] = {0.f, 0.f, 0.f, 0.f};
    int rbase = row0 + wr * 64 + (lane >> 4) * 4;
#pragma unroll
    for (int m = 0; m < 4; m++) {
#pragma unroll
        for (int j = 0; j < 4; j++) {
            int r = rbase + m * 16 + j;
            if (r >= N_NODES) continue;
            int g = sg[r];
            if (g != curg) {
                if (curg >= 0) {
                    float* ob = gout + (size_t)curg * (3 * 4 * H) + rel * (4 * H) + layer * H + wc * 64 + l15;
#pragma unroll
                    for (int n = 0; n < 4; n++) { atomicAdd(ob + n * 16, run[n]); run[n] = 0.f; }
                }
                curg = g;
            }
#pragma unroll
            for (int n = 0; n < 4; n++) {
                float v = acc[m][n][j] + bs[n];
                v = v > 0.f ? v : as_[n] * v;
                o[(size_t)r * H + wc * 64 + n * 16 + l15] = f2b(v);
                csum[n] += v;
                cssq[n] += v * v;
                run[n] += v;
            }
        }
    }
    if (curg >= 0) {
        float* ob = gout + (size_t)curg * (3 * 4 * H) + rel * (4 * H) + layer * H + wc * 64 + l15;
#pragma unroll
        for (int n = 0; n < 4; n++) atomicAdd(ob + n * 16, run[n]);
    }
    __syncthreads();
    float* smS = (float*)&At[0][0][0];   // 4 KB each, inside retired LDS
    float* smQ = (float*)&Bt[0][0][0];
    int contrib = wr * 4 + (lane >> 4);
#pragma unroll
    for (int n = 0; n < 4; n++) {
        int col = wc * 64 + n * 16 + l15;
        smS[col * 8 + contrib] = csum[n];
        smQ[col * 8 + contrib] = cssq[n];
    }
    __syncthreads();
    if (tid < 128) {
        float s = 0.f, q = 0.f;
#pragma unroll
        for (int i = 0; i < 8; i++) { s += smS[tid * 8 + i]; q += smQ[tid * 8 + i]; }
        atomicAdd(&stats[rel * 256 + tid], s);
        atomicAdd(&stats[rel * 256 + 128 + tid], q);
    }
}

// ---------------- BN stats -> affine (s,t); self-zero stats for next layer ----------------

__global__ void finalize_kernel(float* __restrict__ stats,
                                const float* __restrict__ gamma, const float* __restrict__ beta,
                                float* __restrict__ st) {
    int rel = blockIdx.x, c = threadIdx.x;
    const float invN = 1.f / N_NODES;
    float mu = stats[rel * 256 + c] * invN;
    float var = stats[rel * 256 + 128 + c] * invN - mu * mu;
    float s = gamma[rel * H + c] * rsqrtf(var + EPS);
    st[rel * 2 * H + c] = s;
    st[rel * 2 * H + H + c] = beta[rel * H + c] - mu * s;
    stats[rel * 256 + c] = 0.f;
    stats[rel * 256 + 128 + c] = 0.f;
}

// ---------------- Weight prep ----------------

__global__ void prep1_kernel(const float* __restrict__ Wself, const float* __restrict__ Wneigh,
                             unsigned short* __restrict__ Wbt) {
    int idx = blockIdx.x * 256 + threadIdx.x;
    if (idx >= 3 * H * 128) return;
    int rel = idx / (H * 128), rem = idx % (H * 128);
    int c = rem / 128, k = rem % 128;
    float v = (k < 64) ? Wself[((size_t)rel * 64 + k) * H + c]
                       : Wneigh[((size_t)rel * 64 + (k - 64)) * H + c];
    Wbt[idx] = f2b(v);
}

// merged: blocks 0..383 -> W fold/convert; blocks 384..386 -> bias fold
__global__ void prep_kernel(const float* __restrict__ Wself, const float* __restrict__ Wneigh,
                            const float* __restrict__ b, const float* __restrict__ st,
                            unsigned short* __restrict__ Wbt, float* __restrict__ biasp) {
    if (blockIdx.x < 384) {
        int idx = blockIdx.x * 256 + threadIdx.x;
        int rel = idx / (H * 256), rem = idx % (H * 256);
        int c = rem / 256, k = rem % 256;
        float v;
        if (k < 128) v = st[rel * 2 * H + k] * Wself[((size_t)rel * H + k) * H + c];
        else         v = Wneigh[((size_t)rel * H + (k - 128)) * H + c];
        Wbt[idx] = f2b(v);
    } else if (threadIdx.x < H) {
        int rel = blockIdx.x - 384, c = threadIdx.x;
        const float* t = st + rel * 2 * H + H;
        float s = b[rel * H + c];
        for (int k = 0; k < H; k++) s += t[k] * Wself[((size_t)rel * H + k) * H + c];
        biasp[rel * H + c] = s;
    }
}

// ---------------- Final: mean + BN affine ----------------

__global__ void scale_out_kernel(float* __restrict__ out, const int* __restrict__ seg,
                                 const float* __restrict__ st_all) {
    int i = blockIdx.x * 256 + threadIdx.x;
    if (i >= N_GRAPHS * 3 * 4 * H) return;
    int g = i / (3 * 4 * H), k = i % (3 * 4 * H);
    int rel = k / (4 * H), rem = k % (4 * H), layer = rem / H, c = rem % H;
    const int* sg = seg + rel * N_NODES;
    int lo = 0, hi = N_NODES;
    while (lo < hi) { int m = (lo + hi) >> 1; if (sg[m] < g) lo = m + 1; else hi = m; }
    int start = lo;
    hi = N_NODES;
    while (lo < hi) { int m = (lo + hi) >> 1; if (sg[m] <= g) lo = m + 1; else hi = m; }
    int cnt = lo - start;
    float mean = out[i] / (float)max(cnt, 1);
    const float* st = st_all + ((size_t)layer * 3 + rel) * 2 * H;
    out[i] = st[c] * mean + st[H + c];
}

// ---------------- Orchestration ----------------

extern "C" void kernel_launch(void* const* d_in, const int* in_sizes, int n_in,
                              void* d_out, int out_size, void* d_ws, size_t ws_size,
                              hipStream_t stream) {
    const int* h_idx = (const int*)d_in[0];
    const int* p_idx = (const int*)d_in[1];
    const int* hp_idx = (const int*)d_in[2];
    const int* src = (const int*)d_in[3];
    const int* dst = (const int*)d_in[4];
    const int* seg = (const int*)d_in[5];
    const float* emb_h = (const float*)d_in[6];
    const float* emb_p = (const float*)d_in[7];
    const float* emb_hp = (const float*)d_in[8];
    const float* W1_self = (const float*)d_in[9];
    const float* W1_neigh = (const float*)d_in[10];
    const float* b1 = (const float*)d_in[11];
    const float* a1 = (const float*)d_in[12];
    const float* gamma1 = (const float*)d_in[13];
    const float* beta1 = (const float*)d_in[14];
    const float* W_self = (const float*)d_in[15];
    const float* W_neigh = (const float*)d_in[16];
    const float* b = (const float*)d_in[17];
    const float* a = (const float*)d_in[18];
    const float* gamma = (const float*)d_in[19];
    const float* beta = (const float*)d_in[20];
    float* out = (float*)d_out;

    // workspace
    char* p = (char*)d_ws;
    unsigned short* x0 = (unsigned short*)p; p += (size_t)3 * N_NODES * EMB * 2;   // 19.2 MB
    unsigned short* hpA = (unsigned short*)p; p += (size_t)3 * N_NODES * H * 2;    // 38.4 MB
    unsigned short* hpB = (unsigned short*)p; p += (size_t)3 * N_NODES * H * 2;    // 38.4 MB
    unsigned short* Wbt1 = (unsigned short*)p; p += (size_t)3 * H * 128 * 2;
    unsigned short* Wbt = (unsigned short*)p; p += (size_t)3 * H * 256 * 2;
    unsigned short* emb_bf = (unsigned short*)p; p += (size_t)3 * 257 * EMB * 2;
    float* biasp = (float*)p; p += 3 * H * sizeof(float);
    float* st_all = (float*)p; p += 4 * 3 * 2 * H * sizeof(float);
    float* stats = (float*)p; p += 3 * 256 * sizeof(float);
    int* deg = (int*)p; p += (size_t)3 * N_NODES * 4;
    int* row_ptr = (int*)p; p += (size_t)3 * (N_NODES + 1) * 4;
    int* cur = (int*)p; p += (size_t)3 * N_NODES * 4;
    int* edge_src = (int*)p; p += (size_t)3 * N_EDGES * 4;

    hipMemsetAsync(out, 0, (size_t)N_GRAPHS * 3 * 4 * H * sizeof(float), stream);
    hipMemsetAsync(stats, 0, 3 * 256 * 4, stream);

    // CSR build
    hipMemsetAsync(deg, 0, (size_t)3 * N_NODES * 4, stream);
    dim3 eb((N_EDGES + 255) / 256, 3);
    count_deg_kernel<<<eb, 256, 0, stream>>>(dst, deg);
    scan_kernel<<<3, 1024, 0, stream>>>(deg, row_ptr, cur);
    fill_kernel<<<eb, 256, 0, stream>>>(src, dst, cur, edge_src);

    embed_kernel<<<dim3((N_NODES * EMB / 8 + 255) / 256, 3), 256, 0, stream>>>(
        h_idx, p_idx, hp_idx, emb_h, emb_p, emb_hp, x0);
    embbf_kernel<<<dim3((257 * EMB / 8 + 255) / 256, 3), 256, 0, stream>>>(
        emb_h, emb_p, emb_hp, emb_bf);
    prep1_kernel<<<(3 * H * 128 + 255) / 256, 256, 0, stream>>>(W1_self, W1_neigh, Wbt1);

    dim3 gemm_grid((N_NODES + 127) / 128, 3);

    // ---- layer 1 (K = 64; nmean ld=64 in hpB via emb-table gather; out hpA) ----
    aggregate1_kernel<<<dim3((N_NODES + 31) / 32, 3), 256, 0, stream>>>(
        h_idx, p_idx, hp_idx, emb_bf, row_ptr, edge_src, hpB);
    gemm_kernel<64><<<gemm_grid, 256, 0, stream>>>(
        x0, hpB, Wbt1, b1, a1, hpA, stats, seg, out, 0);
    finalize_kernel<<<3, H, 0, stream>>>(stats, gamma1, beta1, st_all);

    // ---- layers 2-4 (K = 128; out aliases nmean) ----
    unsigned short* xin = hpA;
    unsigned short* xout = hpB;
    for (int l = 0; l < 3; l++) {
        const float* st_prev = st_all + (size_t)l * 3 * 2 * H;
        prep_kernel<<<387, 256, 0, stream>>>(
            W_self + (size_t)l * 3 * H * H, W_neigh + (size_t)l * 3 * H * H,
            b + (size_t)l * 3 * H, st_prev, Wbt, biasp);
        aggregate_kernel<128, true><<<dim3((N_NODES + 15) / 16, 3), 256, 0, stream>>>(
            xin, H, row_ptr, edge_src, st_prev, xout);
        gemm_kernel<128><<<gemm_grid, 256, 0, stream>>>(
            xin, xout, Wbt, biasp, a + (size_t)l * 3 * H, xout, stats, seg, out, l + 1);
        finalize_kernel<<<3, H, 0, stream>>>(
            stats, gamma + (size_t)l * 3 * H, beta + (size_t)l * 3 * H,
            st_all + (size_t)(l + 1) * 3 * 2 * H);
        unsigned short* t = xin; xin = xout; xout = t;
    }

    scale_out_kernel<<<(N_GRAPHS * 3 * 4 * H + 255) / 256, 256, 0, stream>>>(out, seg, st_all);
}

// Round 10
// 760.563 us; speedup vs baseline: 1.5817x; 1.0264x over previous
//
#include <hip/hip_runtime.h>

#define N_NODES 50000
#define N_EDGES 400000
#define N_GRAPHS 64
#define EMB 64
#define H 128
#define EPS 1e-5f

typedef __attribute__((ext_vector_type(8))) short bf16x8;
typedef __attribute__((ext_vector_type(4))) float f32x4;

__device__ __forceinline__ unsigned short f2b(float f) {
    unsigned int u = __builtin_bit_cast(unsigned int, f);
    unsigned int r = (u + 0x7fff + ((u >> 16) & 1)) >> 16;  // RNE
    return (unsigned short)r;
}

// ---------------- CSR build ----------------

__global__ void count_deg_kernel(const int* __restrict__ dst, int* __restrict__ deg) {
    int rel = blockIdx.y;
    int e = blockIdx.x * 256 + threadIdx.x;
    if (e < N_EDGES) atomicAdd(&deg[rel * N_NODES + dst[rel * N_EDGES + e]], 1);
}

// 4 elems/thread, 4096/chunk -> 13 chunks; writes row_ptr AND cur
__global__ void scan_kernel(const int* __restrict__ deg, int* __restrict__ row_ptr,
                            int* __restrict__ cur) {
    int rel = blockIdx.x;
    const int* d = deg + rel * N_NODES;
    int* rp = row_ptr + rel * (N_NODES + 1);
    int* cu = cur + rel * N_NODES;
    __shared__ int sm[1024];
    __shared__ int carry;
    if (threadIdx.x == 0) carry = 0;
    __syncthreads();
    for (int base = 0; base < N_NODES; base += 4096) {
        int i0 = base + (int)threadIdx.x * 4;
        int v[4];
        int s = 0;
#pragma unroll
        for (int k = 0; k < 4; k++) { v[k] = (i0 + k < N_NODES) ? d[i0 + k] : 0; s += v[k]; }
        sm[threadIdx.x] = s;
        __syncthreads();
        for (int off = 1; off < 1024; off <<= 1) {
            int t = (threadIdx.x >= off) ? sm[threadIdx.x - off] : 0;
            __syncthreads();
            sm[threadIdx.x] += t;
            __syncthreads();
        }
        int run = carry + sm[threadIdx.x] - s;
#pragma unroll
        for (int k = 0; k < 4; k++) {
            if (i0 + k < N_NODES) { rp[i0 + k] = run; cu[i0 + k] = run; }
            run += v[k];
        }
        __syncthreads();
        if (threadIdx.x == 1023) carry += sm[1023];
        __syncthreads();
    }
    if (threadIdx.x == 0) rp[N_NODES] = carry;
}

__global__ void fill_kernel(const int* __restrict__ src, const int* __restrict__ dst,
                            int* __restrict__ cur, int* __restrict__ edge_src) {
    int rel = blockIdx.y;
    int e = blockIdx.x * 256 + threadIdx.x;
    if (e < N_EDGES) {
        int dn = dst[rel * N_EDGES + e];
        int pos = atomicAdd(&cur[rel * N_NODES + dn], 1);
        edge_src[rel * N_EDGES + pos] = src[rel * N_EDGES + e];
    }
}

// ---------------- Fused init: layer-1 weights + bf16 emb tables ----------------
// blocks [0,192): Wbt1 convert; blocks [192,217): emb -> bf16 tables

__global__ void prep_init_kernel(const float* __restrict__ W1self, const float* __restrict__ W1neigh,
                                 unsigned short* __restrict__ Wbt1,
                                 const float* __restrict__ emb_h, const float* __restrict__ emb_p,
                                 const float* __restrict__ emb_hp,
                                 unsigned short* __restrict__ emb_bf) {
    if (blockIdx.x < 192) {
        int idx = blockIdx.x * 256 + threadIdx.x;  // 3*H*128 = 49152
        int rel = idx / (H * 128), rem = idx % (H * 128);
        int c = rem / 128, k = rem % 128;
        float v = (k < 64) ? W1self[((size_t)rel * 64 + k) * H + c]
                           : W1neigh[((size_t)rel * 64 + (k - 64)) * H + c];
        Wbt1[idx] = f2b(v);
    } else {
        int i = (blockIdx.x - 192) * 256 + threadIdx.x;  // 8-elem units, 3*2056 total
        if (i >= 3 * 257 * EMB / 8) return;
        int rel = i / (257 * EMB / 8), j = i % (257 * EMB / 8);
        const float* emb = rel == 0 ? emb_h : (rel == 1 ? emb_p : emb_hp);
        const float* e = emb + (size_t)j * 8;
        unsigned short o[8];
#pragma unroll
        for (int k = 0; k < 8; k++) o[k] = f2b(e[k]);
        *(uint4*)&emb_bf[(size_t)rel * 257 * EMB + (size_t)j * 8] = *(uint4*)o;
    }
}

// ---------------- Layer-1 aggregation via emb tables (cache-resident) ----------------

__global__ __launch_bounds__(256) void aggregate1_kernel(
        const int* __restrict__ h_idx, const int* __restrict__ p_idx,
        const int* __restrict__ hp_idx,
        const unsigned short* __restrict__ emb_bf,   // [3][257][64]
        const int* __restrict__ row_ptr, const int* __restrict__ edge_src,
        unsigned short* __restrict__ nmean) {
    const int TPN = 8;
    int rel = blockIdx.y;
    int node = blockIdx.x * 32 + threadIdx.x / TPN;
    int c8 = (threadIdx.x % TPN) * 8;
    if (node >= N_NODES) return;
    const int* idxarr = rel == 0 ? h_idx : (rel == 1 ? p_idx : hp_idx);
    const unsigned short* emb = emb_bf + (size_t)rel * 257 * EMB;
    const int* rp = row_ptr + rel * (N_NODES + 1);
    const int* es = edge_src + rel * N_EDGES;
    int s0 = rp[node], s1 = rp[node + 1];
    float acc[8];
#pragma unroll
    for (int j = 0; j < 8; j++) acc[j] = 0.f;

#define ACCUM(V)                                                                      \
    {                                                                                 \
        unsigned int w[4] = {(V).x, (V).y, (V).z, (V).w};                             \
        _Pragma("unroll") for (int j = 0; j < 4; j++) {                               \
            acc[2 * j] += __builtin_bit_cast(float, w[j] << 16);                      \
            acc[2 * j + 1] += __builtin_bit_cast(float, w[j] & 0xffff0000u);          \
        }                                                                             \
    }

    int e = s0;
    for (; e + 4 <= s1; e += 4) {
        int i0 = idxarr[es[e]], i1 = idxarr[es[e + 1]];
        int i2 = idxarr[es[e + 2]], i3 = idxarr[es[e + 3]];
        uint4 v0 = *(const uint4*)&emb[(size_t)i0 * EMB + c8];
        uint4 v1 = *(const uint4*)&emb[(size_t)i1 * EMB + c8];
        uint4 v2 = *(const uint4*)&emb[(size_t)i2 * EMB + c8];
        uint4 v3 = *(const uint4*)&emb[(size_t)i3 * EMB + c8];
        ACCUM(v0) ACCUM(v1) ACCUM(v2) ACCUM(v3)
    }
    for (; e < s1; e++) {
        uint4 v0 = *(const uint4*)&emb[(size_t)idxarr[es[e]] * EMB + c8];
        ACCUM(v0)
    }
    int deg = s1 - s0;
    float inv = 1.f / (float)max(deg, 1);
    unsigned short o[8];
#pragma unroll
    for (int j = 0; j < 8; j++)
        o[j] = (deg > 0) ? f2b(acc[j] * inv) : (unsigned short)0;
    *(uint4*)&nmean[((size_t)rel * N_NODES + node) * EMB + c8] = *(uint4*)o;
}

// ---------------- Layers 2-4 aggregation (bf16 gather, BN-affine fold) ----------------

template <int DIN, bool FOLD>
__global__ __launch_bounds__(256) void aggregate_kernel(
        const unsigned short* __restrict__ x, int ldx,
        const int* __restrict__ row_ptr, const int* __restrict__ edge_src,
        const float* __restrict__ st,
        unsigned short* __restrict__ nmean) {
    const int TPN = DIN / 8;
    int rel = blockIdx.y;
    int node = blockIdx.x * (256 / TPN) + threadIdx.x / TPN;
    int c8 = (threadIdx.x % TPN) * 8;
    if (node >= N_NODES) return;
    const int* rp = row_ptr + rel * (N_NODES + 1);
    const int* es = edge_src + rel * N_EDGES;
    const unsigned short* xr = x + (size_t)rel * N_NODES * ldx;
    int s0 = rp[node], s1 = rp[node + 1];
    float acc[8];
#pragma unroll
    for (int j = 0; j < 8; j++) acc[j] = 0.f;

    int e = s0;
    for (; e + 4 <= s1; e += 4) {
        int i0 = es[e], i1 = es[e + 1], i2 = es[e + 2], i3 = es[e + 3];
        uint4 v0 = *(const uint4*)&xr[(size_t)i0 * ldx + c8];
        uint4 v1 = *(const uint4*)&xr[(size_t)i1 * ldx + c8];
        uint4 v2 = *(const uint4*)&xr[(size_t)i2 * ldx + c8];
        uint4 v3 = *(const uint4*)&xr[(size_t)i3 * ldx + c8];
        ACCUM(v0) ACCUM(v1) ACCUM(v2) ACCUM(v3)
    }
    for (; e < s1; e++) {
        uint4 v0 = *(const uint4*)&xr[(size_t)es[e] * ldx + c8];
        ACCUM(v0)
    }
#undef ACCUM
    int deg = s1 - s0;
    float inv = 1.f / (float)max(deg, 1);
    unsigned short o[8];
#pragma unroll
    for (int j = 0; j < 8; j++) {
        float m = acc[j] * inv;
        if (FOLD) {
            float s = st[rel * 2 * H + c8 + j];
            float t = st[rel * 2 * H + H + c8 + j];
            m = s * m + t;
        }
        o[j] = (deg > 0) ? f2b(m) : (unsigned short)0;
    }
    *(uint4*)&nmean[((size_t)rel * N_NODES + node) * DIN + c8] = *(uint4*)o;
}

// ---- MFMA GEMM (single-buffer LDS, proven config): hp = PReLU([x | nmean] @ Wbt^T + bias);
//      fp32 col stats; per-graph readout sums fused into epilogue.
//      G1: self-half staged from cache-resident emb_bf via idx (layer 1). ----

template <int KX, bool G1>
__global__ __launch_bounds__(256) void gemm_kernel(
        const unsigned short* __restrict__ x,      // [rel][N][KX] bf16 self input (unused if G1)
        const unsigned short* __restrict__ nmean,  // [rel][N][KX] bf16
        const unsigned short* __restrict__ Wbt,    // [rel][H cols][2*KX] bf16
        const float* __restrict__ bias,            // [rel][H]
        const float* __restrict__ alpha,           // [rel][H]
        unsigned short* __restrict__ out,          // [rel][N][H] bf16 (pre-BN)
        float* __restrict__ stats,
        const int* __restrict__ seg_all,           // [rel][N] sorted graph ids
        float* __restrict__ gout,                  // [G][3][4][H] sum accumulator
        int layer,
        const unsigned short* __restrict__ embt,   // [3][257][64] (G1 only)
        const int* __restrict__ h_idx, const int* __restrict__ p_idx,
        const int* __restrict__ hp_idx) {
    const int KTOT = 2 * KX;
    int rel = blockIdx.y;
    int row0 = blockIdx.x * 128;
    const unsigned short* xr = x + (size_t)rel * N_NODES * KX;
    const unsigned short* nm = nmean + (size_t)rel * N_NODES * KX;
    const unsigned short* W = Wbt + (size_t)rel * H * KTOT;
    unsigned short* o = out + (size_t)rel * N_NODES * H;

    __shared__ __align__(16) short At[128][40];
    __shared__ __align__(16) short Bt[128][40];

    int tid = threadIdx.x;
    int lane = tid & 63;
    int wave = tid >> 6;
    int wr = wave >> 1, wc = wave & 1;
    int l15 = lane & 15;
    int koff = (lane >> 4) * 8;

    f32x4 acc[4][4];
#pragma unroll
    for (int m = 0; m < 4; m++)
#pragma unroll
        for (int n = 0; n < 4; n++) acc[m][n] = (f32x4){0.f, 0.f, 0.f, 0.f};

    int seg = tid & 3;
    int rloc = tid >> 2;

    // G1: hoist per-staged-row embedding indices
    int nid0 = 0, nid1 = 0;
    if (G1) {
        const int* idxarr = rel == 0 ? h_idx : (rel == 1 ? p_idx : hp_idx);
        if (row0 + rloc < N_NODES) nid0 = idxarr[row0 + rloc];
        if (row0 + 64 + rloc < N_NODES) nid1 = idxarr[row0 + 64 + rloc];
    }
    const unsigned short* et = G1 ? (embt + (size_t)rel * 257 * EMB) : nullptr;

    for (int kc = 0; kc < KTOT; kc += 32) {
        const bool selfh = kc < KX;
        const unsigned short* Asrc = selfh ? xr : nm;
        int kb = selfh ? kc : kc - KX;
#pragma unroll
        for (int i = 0; i < 2; i++) {
            int r = i * 64 + rloc;
            int gr = row0 + r;
            uint4 v = make_uint4(0u, 0u, 0u, 0u);
            if (gr < N_NODES) {
                if (G1 && selfh) {
                    int nid = i ? nid1 : nid0;
                    v = *(const uint4*)&et[(size_t)nid * EMB + kb + seg * 8];
                } else {
                    v = *(const uint4*)&Asrc[(size_t)gr * KX + kb + seg * 8];
                }
            }
            *(uint4*)&At[r][seg * 8] = v;
        }
#pragma unroll
        for (int i = 0; i < 2; i++) {
            int c = i * 64 + rloc;
            *(uint4*)&Bt[c][seg * 8] = *(const uint4*)&W[(size_t)c * KTOT + kc + seg * 8];
        }
        __syncthreads();
        bf16x8 a[4], b[4];
#pragma unroll
        for (int m = 0; m < 4; m++) a[m] = *(const bf16x8*)&At[wr * 64 + m * 16 + l15][koff];
#pragma unroll
        for (int n = 0; n < 4; n++) b[n] = *(const bf16x8*)&Bt[wc * 64 + n * 16 + l15][koff];
#pragma unroll
        for (int m = 0; m < 4; m++)
#pragma unroll
            for (int n = 0; n < 4; n++)
                acc[m][n] = __builtin_amdgcn_mfma_f32_16x16x32_bf16(a[m], b[n], acc[m][n], 0, 0, 0);
        __syncthreads();
    }

    // epilogue: bias + PReLU, bf16 store, fp32 column stats, per-graph run sums
    float bs[4], as_[4];
#pragma unroll
    for (int n = 0; n < 4; n++) {
        int col = wc * 64 + n * 16 + l15;
        bs[n] = bias[rel * H + col];
        as_[n] = alpha[rel * H + col];
    }
    const int* sg = seg_all + rel * N_NODES;
    float csum[4] = {0.f, 0.f, 0.f, 0.f}, cssq[4] = {0.f, 0.f, 0.f, 0.f};
    int curg = -1;
    float run[4] = {0.f, 0.f, 0.f, 0.f};
    int rbase = row0 + wr * 64 + (lane >> 4) * 4;
#pragma unroll
    for (int m = 0; m < 4; m++) {
#pragma unroll
        for (int j = 0; j < 4; j++) {
            int r = rbase + m * 16 + j;
            if (r >= N_NODES) continue;
            int g = sg[r];
            if (g != curg) {
                if (curg >= 0) {
                    float* ob = gout + (size_t)curg * (3 * 4 * H) + rel * (4 * H) + layer * H + wc * 64 + l15;
#pragma unroll
                    for (int n = 0; n < 4; n++) { atomicAdd(ob + n * 16, run[n]); run[n] = 0.f; }
                }
                curg = g;
            }
#pragma unroll
            for (int n = 0; n < 4; n++) {
                float v = acc[m][n][j] + bs[n];
                v = v > 0.f ? v : as_[n] * v;
                o[(size_t)r * H + wc * 64 + n * 16 + l15] = f2b(v);
                csum[n] += v;
                cssq[n] += v * v;
                run[n] += v;
            }
        }
    }
    if (curg >= 0) {
        float* ob = gout + (size_t)curg * (3 * 4 * H) + rel * (4 * H) + layer * H + wc * 64 + l15;
#pragma unroll
        for (int n = 0; n < 4; n++) atomicAdd(ob + n * 16, run[n]);
    }
    __syncthreads();
    float* smS = (float*)&At[0][0];   // 128 cols x 8 contributors = 4 KB
    float* smQ = (float*)&Bt[0][0];
    int contrib = wr * 4 + (lane >> 4);
#pragma unroll
    for (int n = 0; n < 4; n++) {
        int col = wc * 64 + n * 16 + l15;
        smS[col * 8 + contrib] = csum[n];
        smQ[col * 8 + contrib] = cssq[n];
    }
    __syncthreads();
    if (tid < 128) {
        float s = 0.f, q = 0.f;
#pragma unroll
        for (int i = 0; i < 8; i++) { s += smS[tid * 8 + i]; q += smQ[tid * 8 + i]; }
        atomicAdd(&stats[rel * 256 + tid], s);
        atomicAdd(&stats[rel * 256 + 128 + tid], q);
    }
}

// ---------------- BN stats -> affine (s,t); self-zero stats for next layer ----------------

__global__ void finalize_kernel(float* __restrict__ stats,
                                const float* __restrict__ gamma, const float* __restrict__ beta,
                                float* __restrict__ st) {
    int rel = blockIdx.x, c = threadIdx.x;
    const float invN = 1.f / N_NODES;
    float mu = stats[rel * 256 + c] * invN;
    float var = stats[rel * 256 + 128 + c] * invN - mu * mu;
    float s = gamma[rel * H + c] * rsqrtf(var + EPS);
    st[rel * 2 * H + c] = s;
    st[rel * 2 * H + H + c] = beta[rel * H + c] - mu * s;
    stats[rel * 256 + c] = 0.f;
    stats[rel * 256 + 128 + c] = 0.f;
}

// ---------------- Weight prep (layers 2-4) ----------------
// blocks 0..383 -> W fold/convert; blocks 384..386 -> bias fold

__global__ void prep_kernel(const float* __restrict__ Wself, const float* __restrict__ Wneigh,
                            const float* __restrict__ b, const float* __restrict__ st,
                            unsigned short* __restrict__ Wbt, float* __restrict__ biasp) {
    if (blockIdx.x < 384) {
        int idx = blockIdx.x * 256 + threadIdx.x;
        int rel = idx / (H * 256), rem = idx % (H * 256);
        int c = rem / 256, k = rem % 256;
        float v;
        if (k < 128) v = st[rel * 2 * H + k] * Wself[((size_t)rel * H + k) * H + c];
        else         v = Wneigh[((size_t)rel * H + (k - 128)) * H + c];
        Wbt[idx] = f2b(v);
    } else if (threadIdx.x < H) {
        int rel = blockIdx.x - 384, c = threadIdx.x;
        const float* t = st + rel * 2 * H + H;
        float s = b[rel * H + c];
        for (int k = 0; k < H; k++) s += t[k] * Wself[((size_t)rel * H + k) * H + c];
        biasp[rel * H + c] = s;
    }
}

// ---------------- Final: mean + BN affine ----------------

__global__ void scale_out_kernel(float* __restrict__ out, const int* __restrict__ seg,
                                 const float* __restrict__ st_all) {
    int i = blockIdx.x * 256 + threadIdx.x;
    if (i >= N_GRAPHS * 3 * 4 * H) return;
    int g = i / (3 * 4 * H), k = i % (3 * 4 * H);
    int rel = k / (4 * H), rem = k % (4 * H), layer = rem / H, c = rem % H;
    const int* sg = seg + rel * N_NODES;
    int lo = 0, hi = N_NODES;
    while (lo < hi) { int m = (lo + hi) >> 1; if (sg[m] < g) lo = m + 1; else hi = m; }
    int start = lo;
    hi = N_NODES;
    while (lo < hi) { int m = (lo + hi) >> 1; if (sg[m] <= g) lo = m + 1; else hi = m; }
    int cnt = lo - start;
    float mean = out[i] / (float)max(cnt, 1);
    const float* st = st_all + ((size_t)layer * 3 + rel) * 2 * H;
    out[i] = st[c] * mean + st[H + c];
}

// ---------------- Orchestration ----------------

extern "C" void kernel_launch(void* const* d_in, const int* in_sizes, int n_in,
                              void* d_out, int out_size, void* d_ws, size_t ws_size,
                              hipStream_t stream) {
    const int* h_idx = (const int*)d_in[0];
    const int* p_idx = (const int*)d_in[1];
    const int* hp_idx = (const int*)d_in[2];
    const int* src = (const int*)d_in[3];
    const int* dst = (const int*)d_in[4];
    const int* seg = (const int*)d_in[5];
    const float* emb_h = (const float*)d_in[6];
    const float* emb_p = (const float*)d_in[7];
    const float* emb_hp = (const float*)d_in[8];
    const float* W1_self = (const float*)d_in[9];
    const float* W1_neigh = (const float*)d_in[10];
    const float* b1 = (const float*)d_in[11];
    const float* a1 = (const float*)d_in[12];
    const float* gamma1 = (const float*)d_in[13];
    const float* beta1 = (const float*)d_in[14];
    const float* W_self = (const float*)d_in[15];
    const float* W_neigh = (const float*)d_in[16];
    const float* b = (const float*)d_in[17];
    const float* a = (const float*)d_in[18];
    const float* gamma = (const float*)d_in[19];
    const float* beta = (const float*)d_in[20];
    float* out = (float*)d_out;

    // workspace
    char* p = (char*)d_ws;
    unsigned short* hpA = (unsigned short*)p; p += (size_t)3 * N_NODES * H * 2;    // 38.4 MB
    unsigned short* hpB = (unsigned short*)p; p += (size_t)3 * N_NODES * H * 2;    // 38.4 MB
    unsigned short* Wbt1 = (unsigned short*)p; p += (size_t)3 * H * 128 * 2;
    unsigned short* Wbt = (unsigned short*)p; p += (size_t)3 * H * 256 * 2;
    unsigned short* emb_bf = (unsigned short*)p; p += (size_t)3 * 257 * EMB * 2;
    float* biasp = (float*)p; p += 3 * H * sizeof(float);
    float* st_all = (float*)p; p += 4 * 3 * 2 * H * sizeof(float);
    float* stats = (float*)p; p += 3 * 256 * sizeof(float);
    int* deg = (int*)p; p += (size_t)3 * N_NODES * 4;
    int* row_ptr = (int*)p; p += (size_t)3 * (N_NODES + 1) * 4;
    int* cur = (int*)p; p += (size_t)3 * N_NODES * 4;
    int* edge_src = (int*)p; p += (size_t)3 * N_EDGES * 4;

    hipMemsetAsync(out, 0, (size_t)N_GRAPHS * 3 * 4 * H * sizeof(float), stream);
    hipMemsetAsync(stats, 0, 3 * 256 * 4, stream);

    // CSR build
    hipMemsetAsync(deg, 0, (size_t)3 * N_NODES * 4, stream);
    dim3 eb((N_EDGES + 255) / 256, 3);
    count_deg_kernel<<<eb, 256, 0, stream>>>(dst, deg);
    scan_kernel<<<3, 1024, 0, stream>>>(deg, row_ptr, cur);
    fill_kernel<<<eb, 256, 0, stream>>>(src, dst, cur, edge_src);

    prep_init_kernel<<<217, 256, 0, stream>>>(W1_self, W1_neigh, Wbt1,
                                              emb_h, emb_p, emb_hp, emb_bf);

    dim3 gemm_grid((N_NODES + 127) / 128, 3);

    // ---- layer 1 (K = 64; nmean ld=64 in hpB via emb-table gather; out hpA) ----
    aggregate1_kernel<<<dim3((N_NODES + 31) / 32, 3), 256, 0, stream>>>(
        h_idx, p_idx, hp_idx, emb_bf, row_ptr, edge_src, hpB);
    gemm_kernel<64, true><<<gemm_grid, 256, 0, stream>>>(
        emb_bf /*unused*/, hpB, Wbt1, b1, a1, hpA, stats, seg, out, 0,
        emb_bf, h_idx, p_idx, hp_idx);
    finalize_kernel<<<3, H, 0, stream>>>(stats, gamma1, beta1, st_all);

    // ---- layers 2-4 (K = 128; out aliases nmean) ----
    unsigned short* xin = hpA;
    unsigned short* xout = hpB;
    for (int l = 0; l < 3; l++) {
        const float* st_prev = st_all + (size_t)l * 3 * 2 * H;
        prep_kernel<<<387, 256, 0, stream>>>(
            W_self + (size_t)l * 3 * H * H, W_neigh + (size_t)l * 3 * H * H,
            b + (size_t)l * 3 * H, st_prev, Wbt, biasp);
        aggregate_kernel<128, true><<<dim3((N_NODES + 15) / 16, 3), 256, 0, stream>>>(
            xin, H, row_ptr, edge_src, st_prev, xout);
        gemm_kernel<128, false><<<gemm_grid, 256, 0, stream>>>(
            xin, xout, Wbt, biasp, a + (size_t)l * 3 * H, xout, stats, seg, out, l + 1,
            nullptr, nullptr, nullptr, nullptr);
        finalize_kernel<<<3, H, 0, stream>>>(
            stats, gamma + (size_t)l * 3 * H, beta + (size_t)l * 3 * H,
            st_all + (size_t)(l + 1) * 3 * 2 * H);
        unsigned short* t = xin; xin = xout; xout = t;
    }

    scale_out_kernel<<<(N_GRAPHS * 3 * 4 * H + 255) / 256, 256, 0, stream>>>(out, seg, st_all);
}

// Round 11
// 688.184 us; speedup vs baseline: 1.7481x; 1.1052x over previous
//
#include <hip/hip_runtime.h>

#define N_NODES 50000
#define N_EDGES 400000
#define N_GRAPHS 64
#define EMB 64
#define H 128
#define EPS 1e-5f

#define CH_SHIFT 11               // src chunk = 2048 nodes (512 KB of bf16[128] rows)
#define NC 25                     // ceil(50000 / 2048)

typedef __attribute__((ext_vector_type(8))) short bf16x8;
typedef __attribute__((ext_vector_type(4))) float f32x4;

__device__ __forceinline__ unsigned short f2b(float f) {
    unsigned int u = __builtin_bit_cast(unsigned int, f);
    unsigned int r = (u + 0x7fff + ((u >> 16) & 1)) >> 16;  // RNE
    return (unsigned short)r;
}

// ---------------- CSR build ----------------

__global__ void count_deg_kernel(const int* __restrict__ dst, int* __restrict__ deg) {
    int rel = blockIdx.y;
    int e = blockIdx.x * 256 + threadIdx.x;
    if (e < N_EDGES) atomicAdd(&deg[rel * N_NODES + dst[rel * N_EDGES + e]], 1);
}

// 4 elems/thread, 4096/chunk -> 13 chunks
__global__ void scan_kernel(const int* __restrict__ deg, int* __restrict__ row_ptr) {
    int rel = blockIdx.x;
    const int* d = deg + rel * N_NODES;
    int* rp = row_ptr + rel * (N_NODES + 1);
    __shared__ int sm[1024];
    __shared__ int carry;
    if (threadIdx.x == 0) carry = 0;
    __syncthreads();
    for (int base = 0; base < N_NODES; base += 4096) {
        int i0 = base + (int)threadIdx.x * 4;
        int v[4];
        int s = 0;
#pragma unroll
        for (int k = 0; k < 4; k++) { v[k] = (i0 + k < N_NODES) ? d[i0 + k] : 0; s += v[k]; }
        sm[threadIdx.x] = s;
        __syncthreads();
        for (int off = 1; off < 1024; off <<= 1) {
            int t = (threadIdx.x >= off) ? sm[threadIdx.x - off] : 0;
            __syncthreads();
            sm[threadIdx.x] += t;
            __syncthreads();
        }
        int run = carry + sm[threadIdx.x] - s;
#pragma unroll
        for (int k = 0; k < 4; k++) {
            if (i0 + k < N_NODES) rp[i0 + k] = run;
            run += v[k];
        }
        __syncthreads();
        if (threadIdx.x == 1023) carry += sm[1023];
        __syncthreads();
    }
    if (threadIdx.x == 0) rp[N_NODES] = carry;
}

// per-(dst, src-chunk) histogram
__global__ void count2_kernel(const int* __restrict__ src, const int* __restrict__ dst,
                              int* __restrict__ cnt2) {
    int rel = blockIdx.y;
    int e = blockIdx.x * 256 + threadIdx.x;
    if (e < N_EDGES) {
        int sn = src[rel * N_EDGES + e];
        int dn = dst[rel * N_EDGES + e];
        atomicAdd(&cnt2[((size_t)rel * N_NODES + dn) * NC + (sn >> CH_SHIFT)], 1);
    }
}

// per-node prefix: cnt2 -> absolute cursors (in place)
__global__ void chunkscan_kernel(const int* __restrict__ row_ptr, int* __restrict__ cnt2) {
    int i = blockIdx.x * 256 + threadIdx.x;
    if (i >= 3 * N_NODES) return;
    int rel = i / N_NODES, n = i - rel * N_NODES;
    int run = row_ptr[rel * (N_NODES + 1) + n];
    int* c = cnt2 + (size_t)i * NC;
#pragma unroll
    for (int k = 0; k < NC; k++) {
        int t = c[k];
        c[k] = run;
        run += t;
    }
}

// place edges grouped by src-chunk within each dst's list
__global__ void fill2_kernel(const int* __restrict__ src, const int* __restrict__ dst,
                             int* __restrict__ cnt2, int* __restrict__ edge_src) {
    int rel = blockIdx.y;
    int e = blockIdx.x * 256 + threadIdx.x;
    if (e < N_EDGES) {
        int sn = src[rel * N_EDGES + e];
        int dn = dst[rel * N_EDGES + e];
        int pos = atomicAdd(&cnt2[((size_t)rel * N_NODES + dn) * NC + (sn >> CH_SHIFT)], 1);
        edge_src[rel * N_EDGES + pos] = sn;
    }
}

// ---------------- Fused init: layer-1 weights + bf16 emb tables ----------------

__global__ void prep_init_kernel(const float* __restrict__ W1self, const float* __restrict__ W1neigh,
                                 unsigned short* __restrict__ Wbt1,
                                 const float* __restrict__ emb_h, const float* __restrict__ emb_p,
                                 const float* __restrict__ emb_hp,
                                 unsigned short* __restrict__ emb_bf) {
    if (blockIdx.x < 192) {
        int idx = blockIdx.x * 256 + threadIdx.x;  // 3*H*128 = 49152
        int rel = idx / (H * 128), rem = idx % (H * 128);
        int c = rem / 128, k = rem % 128;
        float v = (k < 64) ? W1self[((size_t)rel * 64 + k) * H + c]
                           : W1neigh[((size_t)rel * 64 + (k - 64)) * H + c];
        Wbt1[idx] = f2b(v);
    } else {
        int i = (blockIdx.x - 192) * 256 + threadIdx.x;
        if (i >= 3 * 257 * EMB / 8) return;
        int rel = i / (257 * EMB / 8), j = i % (257 * EMB / 8);
        const float* emb = rel == 0 ? emb_h : (rel == 1 ? emb_p : emb_hp);
        const float* e = emb + (size_t)j * 8;
        unsigned short o[8];
#pragma unroll
        for (int k = 0; k < 8; k++) o[k] = f2b(e[k]);
        *(uint4*)&emb_bf[(size_t)rel * 257 * EMB + (size_t)j * 8] = *(uint4*)o;
    }
}

// ---------------- Layer-1 aggregation via emb tables (cache-resident) ----------------

__global__ __launch_bounds__(256) void aggregate1_kernel(
        const int* __restrict__ h_idx, const int* __restrict__ p_idx,
        const int* __restrict__ hp_idx,
        const unsigned short* __restrict__ emb_bf,   // [3][257][64]
        const int* __restrict__ row_ptr, const int* __restrict__ edge_src,
        unsigned short* __restrict__ nmean) {
    const int TPN = 8;
    int rel = blockIdx.y;
    int node = blockIdx.x * 32 + threadIdx.x / TPN;
    int c8 = (threadIdx.x % TPN) * 8;
    if (node >= N_NODES) return;
    const int* idxarr = rel == 0 ? h_idx : (rel == 1 ? p_idx : hp_idx);
    const unsigned short* emb = emb_bf + (size_t)rel * 257 * EMB;
    const int* rp = row_ptr + rel * (N_NODES + 1);
    const int* es = edge_src + rel * N_EDGES;
    int s0 = rp[node], s1 = rp[node + 1];
    float acc[8];
#pragma unroll
    for (int j = 0; j < 8; j++) acc[j] = 0.f;

#define ACCUM(V)                                                                      \
    {                                                                                 \
        unsigned int w[4] = {(V).x, (V).y, (V).z, (V).w};                             \
        _Pragma("unroll") for (int j = 0; j < 4; j++) {                               \
            acc[2 * j] += __builtin_bit_cast(float, w[j] << 16);                      \
            acc[2 * j + 1] += __builtin_bit_cast(float, w[j] & 0xffff0000u);          \
        }                                                                             \
    }

    int e = s0;
    for (; e + 4 <= s1; e += 4) {
        int i0 = idxarr[es[e]], i1 = idxarr[es[e + 1]];
        int i2 = idxarr[es[e + 2]], i3 = idxarr[es[e + 3]];
        uint4 v0 = *(const uint4*)&emb[(size_t)i0 * EMB + c8];
        uint4 v1 = *(const uint4*)&emb[(size_t)i1 * EMB + c8];
        uint4 v2 = *(const uint4*)&emb[(size_t)i2 * EMB + c8];
        uint4 v3 = *(const uint4*)&emb[(size_t)i3 * EMB + c8];
        ACCUM(v0) ACCUM(v1) ACCUM(v2) ACCUM(v3)
    }
    for (; e < s1; e++) {
        uint4 v0 = *(const uint4*)&emb[(size_t)idxarr[es[e]] * EMB + c8];
        ACCUM(v0)
    }
    int deg = s1 - s0;
    float inv = 1.f / (float)max(deg, 1);
    unsigned short o[8];
#pragma unroll
    for (int j = 0; j < 8; j++)
        o[j] = (deg > 0) ? f2b(acc[j] * inv) : (unsigned short)0;
    *(uint4*)&nmean[((size_t)rel * N_NODES + node) * EMB + c8] = *(uint4*)o;
}

// ---------------- Layers 2-4 aggregation ----------------
// Long-lived blocks (96 nodes each, 6 batches of 16) so all blocks are resident
// from t=0 and sweep their chunk-sorted adjacency in phase -> src working set
// per XCD stays ~1-2 chunks (0.5-1 MB) per rel at any instant.

template <bool FOLD>
__global__ __launch_bounds__(256) void aggregate_kernel(
        const unsigned short* __restrict__ x,      // [rel][N][128] bf16
        const int* __restrict__ row_ptr, const int* __restrict__ edge_src,
        const float* __restrict__ st,
        unsigned short* __restrict__ nmean) {
    const int TPN = 16;
    int rel = blockIdx.y;
    int c8 = (threadIdx.x % TPN) * 8;
    int nloc = threadIdx.x / TPN;               // 0..15
    const int* rp = row_ptr + rel * (N_NODES + 1);
    const int* es = edge_src + rel * N_EDGES;
    const unsigned short* xr = x + (size_t)rel * N_NODES * H;

    float sj[8], tj[8];
    if (FOLD) {
#pragma unroll
        for (int j = 0; j < 8; j++) {
            sj[j] = st[rel * 2 * H + c8 + j];
            tj[j] = st[rel * 2 * H + H + c8 + j];
        }
    }

#define ACCUM(V)                                                                      \
    {                                                                                 \
        unsigned int w[4] = {(V).x, (V).y, (V).z, (V).w};                             \
        _Pragma("unroll") for (int j = 0; j < 4; j++) {                               \
            acc[2 * j] += __builtin_bit_cast(float, w[j] << 16);                      \
            acc[2 * j + 1] += __builtin_bit_cast(float, w[j] & 0xffff0000u);          \
        }                                                                             \
    }

#pragma unroll
    for (int batch = 0; batch < 6; batch++) {
        int node = blockIdx.x * 96 + batch * 16 + nloc;
        if (node >= N_NODES) continue;
        int s0 = rp[node], s1 = rp[node + 1];
        float acc[8];
#pragma unroll
        for (int j = 0; j < 8; j++) acc[j] = 0.f;
        int e = s0;
        for (; e + 4 <= s1; e += 4) {
            int i0 = es[e], i1 = es[e + 1], i2 = es[e + 2], i3 = es[e + 3];
            uint4 v0 = *(const uint4*)&xr[(size_t)i0 * H + c8];
            uint4 v1 = *(const uint4*)&xr[(size_t)i1 * H + c8];
            uint4 v2 = *(const uint4*)&xr[(size_t)i2 * H + c8];
            uint4 v3 = *(const uint4*)&xr[(size_t)i3 * H + c8];
            ACCUM(v0) ACCUM(v1) ACCUM(v2) ACCUM(v3)
        }
        for (; e < s1; e++) {
            uint4 v0 = *(const uint4*)&xr[(size_t)es[e] * H + c8];
            ACCUM(v0)
        }
        int deg = s1 - s0;
        float inv = 1.f / (float)max(deg, 1);
        unsigned short o[8];
#pragma unroll
        for (int j = 0; j < 8; j++) {
            float m = acc[j] * inv;
            if (FOLD) m = sj[j] * m + tj[j];
            o[j] = (deg > 0) ? f2b(m) : (unsigned short)0;
        }
        *(uint4*)&nmean[((size_t)rel * N_NODES + node) * H + c8] = *(uint4*)o;
    }
#undef ACCUM
}

// ---- MFMA GEMM (single-buffer LDS, proven config): hp = PReLU([x | nmean] @ Wbt^T + bias);
//      fp32 col stats; per-graph readout sums fused into epilogue.
//      G1: self-half staged from cache-resident emb_bf via idx (layer 1). ----

template <int KX, bool G1>
__global__ __launch_bounds__(256) void gemm_kernel(
        const unsigned short* __restrict__ x,
        const unsigned short* __restrict__ nmean,
        const unsigned short* __restrict__ Wbt,
        const float* __restrict__ bias,
        const float* __restrict__ alpha,
        unsigned short* __restrict__ out,
        float* __restrict__ stats,
        const int* __restrict__ seg_all,
        float* __restrict__ gout,
        int layer,
        const unsigned short* __restrict__ embt,
        const int* __restrict__ h_idx, const int* __restrict__ p_idx,
        const int* __restrict__ hp_idx) {
    const int KTOT = 2 * KX;
    int rel = blockIdx.y;
    int row0 = blockIdx.x * 128;
    const unsigned short* xr = x + (size_t)rel * N_NODES * KX;
    const unsigned short* nm = nmean + (size_t)rel * N_NODES * KX;
    const unsigned short* W = Wbt + (size_t)rel * H * KTOT;
    unsigned short* o = out + (size_t)rel * N_NODES * H;

    __shared__ __align__(16) short At[128][40];
    __shared__ __align__(16) short Bt[128][40];

    int tid = threadIdx.x;
    int lane = tid & 63;
    int wave = tid >> 6;
    int wr = wave >> 1, wc = wave & 1;
    int l15 = lane & 15;
    int koff = (lane >> 4) * 8;

    f32x4 acc[4][4];
#pragma unroll
    for (int m = 0; m < 4; m++)
#pragma unroll
        for (int n = 0; n < 4; n++) acc[m][n] = (f32x4){0.f, 0.f, 0.f, 0.f};

    int seg = tid & 3;
    int rloc = tid >> 2;

    int nid0 = 0, nid1 = 0;
    if (G1) {
        const int* idxarr = rel == 0 ? h_idx : (rel == 1 ? p_idx : hp_idx);
        if (row0 + rloc < N_NODES) nid0 = idxarr[row0 + rloc];
        if (row0 + 64 + rloc < N_NODES) nid1 = idxarr[row0 + 64 + rloc];
    }
    const unsigned short* et = G1 ? (embt + (size_t)rel * 257 * EMB) : nullptr;

    for (int kc = 0; kc < KTOT; kc += 32) {
        const bool selfh = kc < KX;
        const unsigned short* Asrc = selfh ? xr : nm;
        int kb = selfh ? kc : kc - KX;
#pragma unroll
        for (int i = 0; i < 2; i++) {
            int r = i * 64 + rloc;
            int gr = row0 + r;
            uint4 v = make_uint4(0u, 0u, 0u, 0u);
            if (gr < N_NODES) {
                if (G1 && selfh) {
                    int nid = i ? nid1 : nid0;
                    v = *(const uint4*)&et[(size_t)nid * EMB + kb + seg * 8];
                } else {
                    v = *(const uint4*)&Asrc[(size_t)gr * KX + kb + seg * 8];
                }
            }
            *(uint4*)&At[r][seg * 8] = v;
        }
#pragma unroll
        for (int i = 0; i < 2; i++) {
            int c = i * 64 + rloc;
            *(uint4*)&Bt[c][seg * 8] = *(const uint4*)&W[(size_t)c * KTOT + kc + seg * 8];
        }
        __syncthreads();
        bf16x8 a[4], b[4];
#pragma unroll
        for (int m = 0; m < 4; m++) a[m] = *(const bf16x8*)&At[wr * 64 + m * 16 + l15][koff];
#pragma unroll
        for (int n = 0; n < 4; n++) b[n] = *(const bf16x8*)&Bt[wc * 64 + n * 16 + l15][koff];
#pragma unroll
        for (int m = 0; m < 4; m++)
#pragma unroll
            for (int n = 0; n < 4; n++)
                acc[m][n] = __builtin_amdgcn_mfma_f32_16x16x32_bf16(a[m], b[n], acc[m][n], 0, 0, 0);
        __syncthreads();
    }

    float bs[4], as_[4];
#pragma unroll
    for (int n = 0; n < 4; n++) {
        int col = wc * 64 + n * 16 + l15;
        bs[n] = bias[rel * H + col];
        as_[n] = alpha[rel * H + col];
    }
    const int* sg = seg_all + rel * N_NODES;
    float csum[4] = {0.f, 0.f, 0.f, 0.f}, cssq[4] = {0.f, 0.f, 0.f, 0.f};
    int curg = -1;
    float run[4] = {0.f, 0.f, 0.f, 0.f};
    int rbase = row0 + wr * 64 + (lane >> 4) * 4;
#pragma unroll
    for (int m = 0; m < 4; m++) {
#pragma unroll
        for (int j = 0; j < 4; j++) {
            int r = rbase + m * 16 + j;
            if (r >= N_NODES) continue;
            int g = sg[r];
            if (g != curg) {
                if (curg >= 0) {
                    float* ob = gout + (size_t)curg * (3 * 4 * H) + rel * (4 * H) + layer * H + wc * 64 + l15;
#pragma unroll
                    for (int n = 0; n < 4; n++) { atomicAdd(ob + n * 16, run[n]); run[n] = 0.f; }
                }
                curg = g;
            }
#pragma unroll
            for (int n = 0; n < 4; n++) {
                float v = acc[m][n][j] + bs[n];
                v = v > 0.f ? v : as_[n] * v;
                o[(size_t)r * H + wc * 64 + n * 16 + l15] = f2b(v);
                csum[n] += v;
                cssq[n] += v * v;
                run[n] += v;
            }
        }
    }
    if (curg >= 0) {
        float* ob = gout + (size_t)curg * (3 * 4 * H) + rel * (4 * H) + layer * H + wc * 64 + l15;
#pragma unroll
        for (int n = 0; n < 4; n++) atomicAdd(ob + n * 16, run[n]);
    }
    __syncthreads();
    float* smS = (float*)&At[0][0];
    float* smQ = (float*)&Bt[0][0];
    int contrib = wr * 4 + (lane >> 4);
#pragma unroll
    for (int n = 0; n < 4; n++) {
        int col = wc * 64 + n * 16 + l15;
        smS[col * 8 + contrib] = csum[n];
        smQ[col * 8 + contrib] = cssq[n];
    }
    __syncthreads();
    if (tid < 128) {
        float s = 0.f, q = 0.f;
#pragma unroll
        for (int i = 0; i < 8; i++) { s += smS[tid * 8 + i]; q += smQ[tid * 8 + i]; }
        atomicAdd(&stats[rel * 256 + tid], s);
        atomicAdd(&stats[rel * 256 + 128 + tid], q);
    }
}

// ---------------- BN stats -> affine (s,t); self-zero stats ----------------

__global__ void finalize_kernel(float* __restrict__ stats,
                                const float* __restrict__ gamma, const float* __restrict__ beta,
                                float* __restrict__ st) {
    int rel = blockIdx.x, c = threadIdx.x;
    const float invN = 1.f / N_NODES;
    float mu = stats[rel * 256 + c] * invN;
    float var = stats[rel * 256 + 128 + c] * invN - mu * mu;
    float s = gamma[rel * H + c] * rsqrtf(var + EPS);
    st[rel * 2 * H + c] = s;
    st[rel * 2 * H + H + c] = beta[rel * H + c] - mu * s;
    stats[rel * 256 + c] = 0.f;
    stats[rel * 256 + 128 + c] = 0.f;
}

// ---------------- Weight prep (layers 2-4) ----------------

__global__ void prep_kernel(const float* __restrict__ Wself, const float* __restrict__ Wneigh,
                            const float* __restrict__ b, const float* __restrict__ st,
                            unsigned short* __restrict__ Wbt, float* __restrict__ biasp) {
    if (blockIdx.x < 384) {
        int idx = blockIdx.x * 256 + threadIdx.x;
        int rel = idx / (H * 256), rem = idx % (H * 256);
        int c = rem / 256, k = rem % 256;
        float v;
        if (k < 128) v = st[rel * 2 * H + k] * Wself[((size_t)rel * H + k) * H + c];
        else         v = Wneigh[((size_t)rel * H + (k - 128)) * H + c];
        Wbt[idx] = f2b(v);
    } else if (threadIdx.x < H) {
        int rel = blockIdx.x - 384, c = threadIdx.x;
        const float* t = st + rel * 2 * H + H;
        float s = b[rel * H + c];
        for (int k = 0; k < H; k++) s += t[k] * Wself[((size_t)rel * H + k) * H + c];
        biasp[rel * H + c] = s;
    }
}

// ---------------- Final: mean + BN affine ----------------

__global__ void scale_out_kernel(float* __restrict__ out, const int* __restrict__ seg,
                                 const float* __restrict__ st_all) {
    int i = blockIdx.x * 256 + threadIdx.x;
    if (i >= N_GRAPHS * 3 * 4 * H) return;
    int g = i / (3 * 4 * H), k = i % (3 * 4 * H);
    int rel = k / (4 * H), rem = k % (4 * H), layer = rem / H, c = rem % H;
    const int* sg = seg + rel * N_NODES;
    int lo = 0, hi = N_NODES;
    while (lo < hi) { int m = (lo + hi) >> 1; if (sg[m] < g) lo = m + 1; else hi = m; }
    int start = lo;
    hi = N_NODES;
    while (lo < hi) { int m = (lo + hi) >> 1; if (sg[m] <= g) lo = m + 1; else hi = m; }
    int cnt = lo - start;
    float mean = out[i] / (float)max(cnt, 1);
    const float* st = st_all + ((size_t)layer * 3 + rel) * 2 * H;
    out[i] = st[c] * mean + st[H + c];
}

// ---------------- Orchestration ----------------

extern "C" void kernel_launch(void* const* d_in, const int* in_sizes, int n_in,
                              void* d_out, int out_size, void* d_ws, size_t ws_size,
                              hipStream_t stream) {
    const int* h_idx = (const int*)d_in[0];
    const int* p_idx = (const int*)d_in[1];
    const int* hp_idx = (const int*)d_in[2];
    const int* src = (const int*)d_in[3];
    const int* dst = (const int*)d_in[4];
    const int* seg = (const int*)d_in[5];
    const float* emb_h = (const float*)d_in[6];
    const float* emb_p = (const float*)d_in[7];
    const float* emb_hp = (const float*)d_in[8];
    const float* W1_self = (const float*)d_in[9];
    const float* W1_neigh = (const float*)d_in[10];
    const float* b1 = (const float*)d_in[11];
    const float* a1 = (const float*)d_in[12];
    const float* gamma1 = (const float*)d_in[13];
    const float* beta1 = (const float*)d_in[14];
    const float* W_self = (const float*)d_in[15];
    const float* W_neigh = (const float*)d_in[16];
    const float* b = (const float*)d_in[17];
    const float* a = (const float*)d_in[18];
    const float* gamma = (const float*)d_in[19];
    const float* beta = (const float*)d_in[20];
    float* out = (float*)d_out;

    // workspace
    char* p = (char*)d_ws;
    unsigned short* hpA = (unsigned short*)p; p += (size_t)3 * N_NODES * H * 2;    // 38.4 MB
    unsigned short* hpB = (unsigned short*)p; p += (size_t)3 * N_NODES * H * 2;    // 38.4 MB
    unsigned short* Wbt1 = (unsigned short*)p; p += (size_t)3 * H * 128 * 2;
    unsigned short* Wbt = (unsigned short*)p; p += (size_t)3 * H * 256 * 2;
    unsigned short* emb_bf = (unsigned short*)p; p += (size_t)3 * 257 * EMB * 2;
    float* biasp = (float*)p; p += 3 * H * sizeof(float);
    float* st_all = (float*)p; p += 4 * 3 * 2 * H * sizeof(float);
    float* stats = (float*)p; p += 3 * 256 * sizeof(float);
    int* deg = (int*)p; p += (size_t)3 * N_NODES * 4;
    int* row_ptr = (int*)p; p += (size_t)3 * (N_NODES + 1) * 4;
    int* cnt2 = (int*)p; p += (size_t)3 * N_NODES * NC * 4;                        // 15 MB
    int* edge_src = (int*)p; p += (size_t)3 * N_EDGES * 4;

    hipMemsetAsync(out, 0, (size_t)N_GRAPHS * 3 * 4 * H * sizeof(float), stream);
    hipMemsetAsync(stats, 0, 3 * 256 * 4, stream);

    // CSR build (chunk-grouped adjacency)
    hipMemsetAsync(deg, 0, (size_t)3 * N_NODES * 4, stream);
    hipMemsetAsync(cnt2, 0, (size_t)3 * N_NODES * NC * 4, stream);
    dim3 eb((N_EDGES + 255) / 256, 3);
    count_deg_kernel<<<eb, 256, 0, stream>>>(dst, deg);
    scan_kernel<<<3, 1024, 0, stream>>>(deg, row_ptr);
    count2_kernel<<<eb, 256, 0, stream>>>(src, dst, cnt2);
    chunkscan_kernel<<<(3 * N_NODES + 255) / 256, 256, 0, stream>>>(row_ptr, cnt2);
    fill2_kernel<<<eb, 256, 0, stream>>>(src, dst, cnt2, edge_src);

    prep_init_kernel<<<217, 256, 0, stream>>>(W1_self, W1_neigh, Wbt1,
                                              emb_h, emb_p, emb_hp, emb_bf);

    dim3 gemm_grid((N_NODES + 127) / 128, 3);
    dim3 agg_grid((N_NODES + 95) / 96, 3);

    // ---- layer 1 (K = 64; nmean ld=64 in hpB via emb-table gather; out hpA) ----
    aggregate1_kernel<<<dim3((N_NODES + 31) / 32, 3), 256, 0, stream>>>(
        h_idx, p_idx, hp_idx, emb_bf, row_ptr, edge_src, hpB);
    gemm_kernel<64, true><<<gemm_grid, 256, 0, stream>>>(
        emb_bf /*unused*/, hpB, Wbt1, b1, a1, hpA, stats, seg, out, 0,
        emb_bf, h_idx, p_idx, hp_idx);
    finalize_kernel<<<3, H, 0, stream>>>(stats, gamma1, beta1, st_all);

    // ---- layers 2-4 (K = 128; out aliases nmean) ----
    unsigned short* xin = hpA;
    unsigned short* xout = hpB;
    for (int l = 0; l < 3; l++) {
        const float* st_prev = st_all + (size_t)l * 3 * 2 * H;
        prep_kernel<<<387, 256, 0, stream>>>(
            W_self + (size_t)l * 3 * H * H, W_neigh + (size_t)l * 3 * H * H,
            b + (size_t)l * 3 * H, st_prev, Wbt, biasp);
        aggregate_kernel<true><<<agg_grid, 256, 0, stream>>>(
            xin, row_ptr, edge_src, st_prev, xout);
        gemm_kernel<128, false><<<gemm_grid, 256, 0, stream>>>(
            xin, xout, Wbt, biasp, a + (size_t)l * 3 * H, xout, stats, seg, out, l + 1,
            nullptr, nullptr, nullptr, nullptr);
        finalize_kernel<<<3, H, 0, stream>>>(
            stats, gamma + (size_t)l * 3 * H, beta + (size_t)l * 3 * H,
            st_all + (size_t)(l + 1) * 3 * 2 * H);
        unsigned short* t = xin; xin = xout; xout = t;
    }

    scale_out_kernel<<<(N_GRAPHS * 3 * 4 * H + 255) / 256, 256, 0, stream>>>(out, seg, st_all);
}

// Round 12
// 680.459 us; speedup vs baseline: 1.7679x; 1.0114x over previous
//
#include <hip/hip_runtime.h>

#define N_NODES 50000
#define N_EDGES 400000
#define N_GRAPHS 64
#define EMB 64
#define H 128
#define EPS 1e-5f

typedef __attribute__((ext_vector_type(8))) short bf16x8;
typedef __attribute__((ext_vector_type(4))) float f32x4;

__device__ __forceinline__ unsigned short f2b(float f) {
    unsigned int u = __builtin_bit_cast(unsigned int, f);
    unsigned int r = (u + 0x7fff + ((u >> 16) & 1)) >> 16;  // RNE
    return (unsigned short)r;
}

// ---------------- CSR build ----------------

__global__ void count_deg_kernel(const int* __restrict__ dst, int* __restrict__ deg) {
    int rel = blockIdx.y;
    int e = blockIdx.x * 256 + threadIdx.x;
    if (e < N_EDGES) atomicAdd(&deg[rel * N_NODES + dst[rel * N_EDGES + e]], 1);
}

// 4 elems/thread, 4096/chunk -> 13 chunks; writes row_ptr AND cur
__global__ void scan_kernel(const int* __restrict__ deg, int* __restrict__ row_ptr,
                            int* __restrict__ cur) {
    int rel = blockIdx.x;
    const int* d = deg + rel * N_NODES;
    int* rp = row_ptr + rel * (N_NODES + 1);
    int* cu = cur + rel * N_NODES;
    __shared__ int sm[1024];
    __shared__ int carry;
    if (threadIdx.x == 0) carry = 0;
    __syncthreads();
    for (int base = 0; base < N_NODES; base += 4096) {
        int i0 = base + (int)threadIdx.x * 4;
        int v[4];
        int s = 0;
#pragma unroll
        for (int k = 0; k < 4; k++) { v[k] = (i0 + k < N_NODES) ? d[i0 + k] : 0; s += v[k]; }
        sm[threadIdx.x] = s;
        __syncthreads();
        for (int off = 1; off < 1024; off <<= 1) {
            int t = (threadIdx.x >= off) ? sm[threadIdx.x - off] : 0;
            __syncthreads();
            sm[threadIdx.x] += t;
            __syncthreads();
        }
        int run = carry + sm[threadIdx.x] - s;
#pragma unroll
        for (int k = 0; k < 4; k++) {
            if (i0 + k < N_NODES) { rp[i0 + k] = run; cu[i0 + k] = run; }
            run += v[k];
        }
        __syncthreads();
        if (threadIdx.x == 1023) carry += sm[1023];
        __syncthreads();
    }
    if (threadIdx.x == 0) rp[N_NODES] = carry;
}

__global__ void fill_kernel(const int* __restrict__ src, const int* __restrict__ dst,
                            int* __restrict__ cur, int* __restrict__ edge_src) {
    int rel = blockIdx.y;
    int e = blockIdx.x * 256 + threadIdx.x;
    if (e < N_EDGES) {
        int dn = dst[rel * N_EDGES + e];
        int pos = atomicAdd(&cur[rel * N_NODES + dn], 1);
        edge_src[rel * N_EDGES + pos] = src[rel * N_EDGES + e];
    }
}

// sort each node's adjacency list by src (contiguous ~32B segments, L2-resident)
__global__ void sort_adj_kernel(const int* __restrict__ row_ptr, int* __restrict__ edge_src) {
    int i = blockIdx.x * 256 + threadIdx.x;
    if (i >= 3 * N_NODES) return;
    int rel = i / N_NODES, n = i - rel * N_NODES;
    const int* rp = row_ptr + rel * (N_NODES + 1);
    int* es = edge_src + rel * N_EDGES;
    int s0 = rp[n], s1 = rp[n + 1];
    for (int a = s0 + 1; a < s1; a++) {
        int key = es[a];
        int b = a - 1;
        while (b >= s0 && es[b] > key) { es[b + 1] = es[b]; b--; }
        es[b + 1] = key;
    }
}

// ---------------- Fused init: layer-1 weights + bf16 emb tables ----------------

__global__ void prep_init_kernel(const float* __restrict__ W1self, const float* __restrict__ W1neigh,
                                 unsigned short* __restrict__ Wbt1,
                                 const float* __restrict__ emb_h, const float* __restrict__ emb_p,
                                 const float* __restrict__ emb_hp,
                                 unsigned short* __restrict__ emb_bf) {
    if (blockIdx.x < 192) {
        int idx = blockIdx.x * 256 + threadIdx.x;  // 3*H*128 = 49152
        int rel = idx / (H * 128), rem = idx % (H * 128);
        int c = rem / 128, k = rem % 128;
        float v = (k < 64) ? W1self[((size_t)rel * 64 + k) * H + c]
                           : W1neigh[((size_t)rel * 64 + (k - 64)) * H + c];
        Wbt1[idx] = f2b(v);
    } else {
        int i = (blockIdx.x - 192) * 256 + threadIdx.x;
        if (i >= 3 * 257 * EMB / 8) return;
        int rel = i / (257 * EMB / 8), j = i % (257 * EMB / 8);
        const float* emb = rel == 0 ? emb_h : (rel == 1 ? emb_p : emb_hp);
        const float* e = emb + (size_t)j * 8;
        unsigned short o[8];
#pragma unroll
        for (int k = 0; k < 8; k++) o[k] = f2b(e[k]);
        *(uint4*)&emb_bf[(size_t)rel * 257 * EMB + (size_t)j * 8] = *(uint4*)o;
    }
}

// ---------------- Layer-1 aggregation via emb tables (cache-resident) ----------------

__global__ __launch_bounds__(256) void aggregate1_kernel(
        const int* __restrict__ h_idx, const int* __restrict__ p_idx,
        const int* __restrict__ hp_idx,
        const unsigned short* __restrict__ emb_bf,   // [3][257][64]
        const int* __restrict__ row_ptr, const int* __restrict__ edge_src,
        unsigned short* __restrict__ nmean) {
    const int TPN = 8;
    int rel = blockIdx.y;
    int node = blockIdx.x * 32 + threadIdx.x / TPN;
    int c8 = (threadIdx.x % TPN) * 8;
    if (node >= N_NODES) return;
    const int* idxarr = rel == 0 ? h_idx : (rel == 1 ? p_idx : hp_idx);
    const unsigned short* emb = emb_bf + (size_t)rel * 257 * EMB;
    const int* rp = row_ptr + rel * (N_NODES + 1);
    const int* es = edge_src + rel * N_EDGES;
    int s0 = rp[node], s1 = rp[node + 1];
    float acc[8];
#pragma unroll
    for (int j = 0; j < 8; j++) acc[j] = 0.f;

#define ACCUM(V)                                                                      \
    {                                                                                 \
        unsigned int w[4] = {(V).x, (V).y, (V).z, (V).w};                             \
        _Pragma("unroll") for (int j = 0; j < 4; j++) {                               \
            acc[2 * j] += __builtin_bit_cast(float, w[j] << 16);                      \
            acc[2 * j + 1] += __builtin_bit_cast(float, w[j] & 0xffff0000u);          \
        }                                                                             \
    }

    int e = s0;
    for (; e + 4 <= s1; e += 4) {
        int i0 = idxarr[es[e]], i1 = idxarr[es[e + 1]];
        int i2 = idxarr[es[e + 2]], i3 = idxarr[es[e + 3]];
        uint4 v0 = *(const uint4*)&emb[(size_t)i0 * EMB + c8];
        uint4 v1 = *(const uint4*)&emb[(size_t)i1 * EMB + c8];
        uint4 v2 = *(const uint4*)&emb[(size_t)i2 * EMB + c8];
        uint4 v3 = *(const uint4*)&emb[(size_t)i3 * EMB + c8];
        ACCUM(v0) ACCUM(v1) ACCUM(v2) ACCUM(v3)
    }
    for (; e < s1; e++) {
        uint4 v0 = *(const uint4*)&emb[(size_t)idxarr[es[e]] * EMB + c8];
        ACCUM(v0)
    }
    int deg = s1 - s0;
    float inv = 1.f / (float)max(deg, 1);
    unsigned short o[8];
#pragma unroll
    for (int j = 0; j < 8; j++)
        o[j] = (deg > 0) ? f2b(acc[j] * inv) : (unsigned short)0;
    *(uint4*)&nmean[((size_t)rel * N_NODES + node) * EMB + c8] = *(uint4*)o;
}

// ---------------- Layers 2-4 aggregation ----------------
// Long-lived blocks (96 nodes each, 6 batches of 16); src-sorted adjacency ->
// resident blocks sweep x in phase, keeping the live src window L2-sized.

template <bool FOLD>
__global__ __launch_bounds__(256) void aggregate_kernel(
        const unsigned short* __restrict__ x,      // [rel][N][128] bf16
        const int* __restrict__ row_ptr, const int* __restrict__ edge_src,
        const float* __restrict__ st,
        unsigned short* __restrict__ nmean) {
    const int TPN = 16;
    int rel = blockIdx.y;
    int c8 = (threadIdx.x % TPN) * 8;
    int nloc = threadIdx.x / TPN;               // 0..15
    const int* rp = row_ptr + rel * (N_NODES + 1);
    const int* es = edge_src + rel * N_EDGES;
    const unsigned short* xr = x + (size_t)rel * N_NODES * H;

    float sj[8], tj[8];
    if (FOLD) {
#pragma unroll
        for (int j = 0; j < 8; j++) {
            sj[j] = st[rel * 2 * H + c8 + j];
            tj[j] = st[rel * 2 * H + H + c8 + j];
        }
    }

#pragma unroll
    for (int batch = 0; batch < 6; batch++) {
        int node = blockIdx.x * 96 + batch * 16 + nloc;
        if (node >= N_NODES) continue;
        int s0 = rp[node], s1 = rp[node + 1];
        float acc[8];
#pragma unroll
        for (int j = 0; j < 8; j++) acc[j] = 0.f;
        int e = s0;
        for (; e + 4 <= s1; e += 4) {
            int i0 = es[e], i1 = es[e + 1], i2 = es[e + 2], i3 = es[e + 3];
            uint4 v0 = *(const uint4*)&xr[(size_t)i0 * H + c8];
            uint4 v1 = *(const uint4*)&xr[(size_t)i1 * H + c8];
            uint4 v2 = *(const uint4*)&xr[(size_t)i2 * H + c8];
            uint4 v3 = *(const uint4*)&xr[(size_t)i3 * H + c8];
            ACCUM(v0) ACCUM(v1) ACCUM(v2) ACCUM(v3)
        }
        for (; e < s1; e++) {
            uint4 v0 = *(const uint4*)&xr[(size_t)es[e] * H + c8];
            ACCUM(v0)
        }
        int deg = s1 - s0;
        float inv = 1.f / (float)max(deg, 1);
        unsigned short o[8];
#pragma unroll
        for (int j = 0; j < 8; j++) {
            float m = acc[j] * inv;
            if (FOLD) m = sj[j] * m + tj[j];
            o[j] = (deg > 0) ? f2b(m) : (unsigned short)0;
        }
        *(uint4*)&nmean[((size_t)rel * N_NODES + node) * H + c8] = *(uint4*)o;
    }
#undef ACCUM
}

// ---- MFMA GEMM (single-buffer LDS, proven config): hp = PReLU([x | nmean] @ Wbt^T + bias);
//      fp32 col stats; per-graph readout sums fused into epilogue.
//      G1: self-half staged from cache-resident emb_bf via idx (layer 1). ----

template <int KX, bool G1>
__global__ __launch_bounds__(256) void gemm_kernel(
        const unsigned short* __restrict__ x,
        const unsigned short* __restrict__ nmean,
        const unsigned short* __restrict__ Wbt,
        const float* __restrict__ bias,
        const float* __restrict__ alpha,
        unsigned short* __restrict__ out,
        float* __restrict__ stats,
        const int* __restrict__ seg_all,
        float* __restrict__ gout,
        int layer,
        const unsigned short* __restrict__ embt,
        const int* __restrict__ h_idx, const int* __restrict__ p_idx,
        const int* __restrict__ hp_idx) {
    const int KTOT = 2 * KX;
    int rel = blockIdx.y;
    int row0 = blockIdx.x * 128;
    const unsigned short* xr = x + (size_t)rel * N_NODES * KX;
    const unsigned short* nm = nmean + (size_t)rel * N_NODES * KX;
    const unsigned short* W = Wbt + (size_t)rel * H * KTOT;
    unsigned short* o = out + (size_t)rel * N_NODES * H;

    __shared__ __align__(16) short At[128][40];
    __shared__ __align__(16) short Bt[128][40];

    int tid = threadIdx.x;
    int lane = tid & 63;
    int wave = tid >> 6;
    int wr = wave >> 1, wc = wave & 1;
    int l15 = lane & 15;
    int koff = (lane >> 4) * 8;

    f32x4 acc[4][4];
#pragma unroll
    for (int m = 0; m < 4; m++)
#pragma unroll
        for (int n = 0; n < 4; n++) acc[m][n] = (f32x4){0.f, 0.f, 0.f, 0.f};

    int seg = tid & 3;
    int rloc = tid >> 2;

    int nid0 = 0, nid1 = 0;
    if (G1) {
        const int* idxarr = rel == 0 ? h_idx : (rel == 1 ? p_idx : hp_idx);
        if (row0 + rloc < N_NODES) nid0 = idxarr[row0 + rloc];
        if (row0 + 64 + rloc < N_NODES) nid1 = idxarr[row0 + 64 + rloc];
    }
    const unsigned short* et = G1 ? (embt + (size_t)rel * 257 * EMB) : nullptr;

    for (int kc = 0; kc < KTOT; kc += 32) {
        const bool selfh = kc < KX;
        const unsigned short* Asrc = selfh ? xr : nm;
        int kb = selfh ? kc : kc - KX;
#pragma unroll
        for (int i = 0; i < 2; i++) {
            int r = i * 64 + rloc;
            int gr = row0 + r;
            uint4 v = make_uint4(0u, 0u, 0u, 0u);
            if (gr < N_NODES) {
                if (G1 && selfh) {
                    int nid = i ? nid1 : nid0;
                    v = *(const uint4*)&et[(size_t)nid * EMB + kb + seg * 8];
                } else {
                    v = *(const uint4*)&Asrc[(size_t)gr * KX + kb + seg * 8];
                }
            }
            *(uint4*)&At[r][seg * 8] = v;
        }
#pragma unroll
        for (int i = 0; i < 2; i++) {
            int c = i * 64 + rloc;
            *(uint4*)&Bt[c][seg * 8] = *(const uint4*)&W[(size_t)c * KTOT + kc + seg * 8];
        }
        __syncthreads();
        bf16x8 a[4], b[4];
#pragma unroll
        for (int m = 0; m < 4; m++) a[m] = *(const bf16x8*)&At[wr * 64 + m * 16 + l15][koff];
#pragma unroll
        for (int n = 0; n < 4; n++) b[n] = *(const bf16x8*)&Bt[wc * 64 + n * 16 + l15][koff];
#pragma unroll
        for (int m = 0; m < 4; m++)
#pragma unroll
            for (int n = 0; n < 4; n++)
                acc[m][n] = __builtin_amdgcn_mfma_f32_16x16x32_bf16(a[m], b[n], acc[m][n], 0, 0, 0);
        __syncthreads();
    }

    float bs[4], as_[4];
#pragma unroll
    for (int n = 0; n < 4; n++) {
        int col = wc * 64 + n * 16 + l15;
        bs[n] = bias[rel * H + col];
        as_[n] = alpha[rel * H + col];
    }
    const int* sg = seg_all + rel * N_NODES;
    float csum[4] = {0.f, 0.f, 0.f, 0.f}, cssq[4] = {0.f, 0.f, 0.f, 0.f};
    int curg = -1;
    float run[4] = {0.f, 0.f, 0.f, 0.f};
    int rbase = row0 + wr * 64 + (lane >> 4) * 4;
#pragma unroll
    for (int m = 0; m < 4; m++) {
#pragma unroll
        for (int j = 0; j < 4; j++) {
            int r = rbase + m * 16 + j;
            if (r >= N_NODES) continue;
            int g = sg[r];
            if (g != curg) {
                if (curg >= 0) {
                    float* ob = gout + (size_t)curg * (3 * 4 * H) + rel * (4 * H) + layer * H + wc * 64 + l15;
#pragma unroll
                    for (int n = 0; n < 4; n++) { atomicAdd(ob + n * 16, run[n]); run[n] = 0.f; }
                }
                curg = g;
            }
#pragma unroll
            for (int n = 0; n < 4; n++) {
                float v = acc[m][n][j] + bs[n];
                v = v > 0.f ? v : as_[n] * v;
                o[(size_t)r * H + wc * 64 + n * 16 + l15] = f2b(v);
                csum[n] += v;
                cssq[n] += v * v;
                run[n] += v;
            }
        }
    }
    if (curg >= 0) {
        float* ob = gout + (size_t)curg * (3 * 4 * H) + rel * (4 * H) + layer * H + wc * 64 + l15;
#pragma unroll
        for (int n = 0; n < 4; n++) atomicAdd(ob + n * 16, run[n]);
    }
    __syncthreads();
    float* smS = (float*)&At[0][0];
    float* smQ = (float*)&Bt[0][0];
    int contrib = wr * 4 + (lane >> 4);
#pragma unroll
    for (int n = 0; n < 4; n++) {
        int col = wc * 64 + n * 16 + l15;
        smS[col * 8 + contrib] = csum[n];
        smQ[col * 8 + contrib] = cssq[n];
    }
    __syncthreads();
    if (tid < 128) {
        float s = 0.f, q = 0.f;
#pragma unroll
        for (int i = 0; i < 8; i++) { s += smS[tid * 8 + i]; q += smQ[tid * 8 + i]; }
        atomicAdd(&stats[rel * 256 + tid], s);
        atomicAdd(&stats[rel * 256 + 128 + tid], q);
    }
}

// ---------------- BN stats -> affine (s,t); self-zero stats ----------------

__global__ void finalize_kernel(float* __restrict__ stats,
                                const float* __restrict__ gamma, const float* __restrict__ beta,
                                float* __restrict__ st) {
    int rel = blockIdx.x, c = threadIdx.x;
    const float invN = 1.f / N_NODES;
    float mu = stats[rel * 256 + c] * invN;
    float var = stats[rel * 256 + 128 + c] * invN - mu * mu;
    float s = gamma[rel * H + c] * rsqrtf(var + EPS);
    st[rel * 2 * H + c] = s;
    st[rel * 2 * H + H + c] = beta[rel * H + c] - mu * s;
    stats[rel * 256 + c] = 0.f;
    stats[rel * 256 + 128 + c] = 0.f;
}

// ---------------- Weight prep (layers 2-4) ----------------

__global__ void prep_kernel(const float* __restrict__ Wself, const float* __restrict__ Wneigh,
                            const float* __restrict__ b, const float* __restrict__ st,
                            unsigned short* __restrict__ Wbt, float* __restrict__ biasp) {
    if (blockIdx.x < 384) {
        int idx = blockIdx.x * 256 + threadIdx.x;
        int rel = idx / (H * 256), rem = idx % (H * 256);
        int c = rem / 256, k = rem % 256;
        float v;
        if (k < 128) v = st[rel * 2 * H + k] * Wself[((size_t)rel * H + k) * H + c];
        else         v = Wneigh[((size_t)rel * H + (k - 128)) * H + c];
        Wbt[idx] = f2b(v);
    } else if (threadIdx.x < H) {
        int rel = blockIdx.x - 384, c = threadIdx.x;
        const float* t = st + rel * 2 * H + H;
        float s = b[rel * H + c];
        for (int k = 0; k < H; k++) s += t[k] * Wself[((size_t)rel * H + k) * H + c];
        biasp[rel * H + c] = s;
    }
}

// ---------------- Final: mean + BN affine ----------------

__global__ void scale_out_kernel(float* __restrict__ out, const int* __restrict__ seg,
                                 const float* __restrict__ st_all) {
    int i = blockIdx.x * 256 + threadIdx.x;
    if (i >= N_GRAPHS * 3 * 4 * H) return;
    int g = i / (3 * 4 * H), k = i % (3 * 4 * H);
    int rel = k / (4 * H), rem = k % (4 * H), layer = rem / H, c = rem % H;
    const int* sg = seg + rel * N_NODES;
    int lo = 0, hi = N_NODES;
    while (lo < hi) { int m = (lo + hi) >> 1; if (sg[m] < g) lo = m + 1; else hi = m; }
    int start = lo;
    hi = N_NODES;
    while (lo < hi) { int m = (lo + hi) >> 1; if (sg[m] <= g) lo = m + 1; else hi = m; }
    int cnt = lo - start;
    float mean = out[i] / (float)max(cnt, 1);
    const float* st = st_all + ((size_t)layer * 3 + rel) * 2 * H;
    out[i] = st[c] * mean + st[H + c];
}

// ---------------- Orchestration ----------------

extern "C" void kernel_launch(void* const* d_in, const int* in_sizes, int n_in,
                              void* d_out, int out_size, void* d_ws, size_t ws_size,
                              hipStream_t stream) {
    const int* h_idx = (const int*)d_in[0];
    const int* p_idx = (const int*)d_in[1];
    const int* hp_idx = (const int*)d_in[2];
    const int* src = (const int*)d_in[3];
    const int* dst = (const int*)d_in[4];
    const int* seg = (const int*)d_in[5];
    const float* emb_h = (const float*)d_in[6];
    const float* emb_p = (const float*)d_in[7];
    const float* emb_hp = (const float*)d_in[8];
    const float* W1_self = (const float*)d_in[9];
    const float* W1_neigh = (const float*)d_in[10];
    const float* b1 = (const float*)d_in[11];
    const float* a1 = (const float*)d_in[12];
    const float* gamma1 = (const float*)d_in[13];
    const float* beta1 = (const float*)d_in[14];
    const float* W_self = (const float*)d_in[15];
    const float* W_neigh = (const float*)d_in[16];
    const float* b = (const float*)d_in[17];
    const float* a = (const float*)d_in[18];
    const float* gamma = (const float*)d_in[19];
    const float* beta = (const float*)d_in[20];
    float* out = (float*)d_out;

    // workspace
    char* p = (char*)d_ws;
    unsigned short* hpA = (unsigned short*)p; p += (size_t)3 * N_NODES * H * 2;    // 38.4 MB
    unsigned short* hpB = (unsigned short*)p; p += (size_t)3 * N_NODES * H * 2;    // 38.4 MB
    unsigned short* Wbt1 = (unsigned short*)p; p += (size_t)3 * H * 128 * 2;
    unsigned short* Wbt = (unsigned short*)p; p += (size_t)3 * H * 256 * 2;
    unsigned short* emb_bf = (unsigned short*)p; p += (size_t)3 * 257 * EMB * 2;
    float* biasp = (float*)p; p += 3 * H * sizeof(float);
    float* st_all = (float*)p; p += 4 * 3 * 2 * H * sizeof(float);
    float* stats = (float*)p; p += 3 * 256 * sizeof(float);
    int* deg = (int*)p; p += (size_t)3 * N_NODES * 4;
    int* row_ptr = (int*)p; p += (size_t)3 * (N_NODES + 1) * 4;
    int* cur = (int*)p; p += (size_t)3 * N_NODES * 4;
    int* edge_src = (int*)p; p += (size_t)3 * N_EDGES * 4;

    hipMemsetAsync(out, 0, (size_t)N_GRAPHS * 3 * 4 * H * sizeof(float), stream);
    hipMemsetAsync(stats, 0, 3 * 256 * 4, stream);

    // CSR build + per-node src-sort
    hipMemsetAsync(deg, 0, (size_t)3 * N_NODES * 4, stream);
    dim3 eb((N_EDGES + 255) / 256, 3);
    count_deg_kernel<<<eb, 256, 0, stream>>>(dst, deg);
    scan_kernel<<<3, 1024, 0, stream>>>(deg, row_ptr, cur);
    fill_kernel<<<eb, 256, 0, stream>>>(src, dst, cur, edge_src);
    sort_adj_kernel<<<(3 * N_NODES + 255) / 256, 256, 0, stream>>>(row_ptr, edge_src);

    prep_init_kernel<<<217, 256, 0, stream>>>(W1_self, W1_neigh, Wbt1,
                                              emb_h, emb_p, emb_hp, emb_bf);

    dim3 gemm_grid((N_NODES + 127) / 128, 3);
    dim3 agg_grid((N_NODES + 95) / 96, 3);

    // ---- layer 1 (K = 64; nmean ld=64 in hpB via emb-table gather; out hpA) ----
    aggregate1_kernel<<<dim3((N_NODES + 31) / 32, 3), 256, 0, stream>>>(
        h_idx, p_idx, hp_idx, emb_bf, row_ptr, edge_src, hpB);
    gemm_kernel<64, true><<<gemm_grid, 256, 0, stream>>>(
        emb_bf /*unused*/, hpB, Wbt1, b1, a1, hpA, stats, seg, out, 0,
        emb_bf, h_idx, p_idx, hp_idx);
    finalize_kernel<<<3, H, 0, stream>>>(stats, gamma1, beta1, st_all);

    // ---- layers 2-4 (K = 128; out aliases nmean) ----
    unsigned short* xin = hpA;
    unsigned short* xout = hpB;
    for (int l = 0; l < 3; l++) {
        const float* st_prev = st_all + (size_t)l * 3 * 2 * H;
        prep_kernel<<<387, 256, 0, stream>>>(
            W_self + (size_t)l * 3 * H * H, W_neigh + (size_t)l * 3 * H * H,
            b + (size_t)l * 3 * H, st_prev, Wbt, biasp);
        aggregate_kernel<true><<<agg_grid, 256, 0, stream>>>(
            xin, row_ptr, edge_src, st_prev, xout);
        gemm_kernel<128, false><<<gemm_grid, 256, 0, stream>>>(
            xin, xout, Wbt, biasp, a + (size_t)l * 3 * H, xout, stats, seg, out, l + 1,
            nullptr, nullptr, nullptr, nullptr);
        finalize_kernel<<<3, H, 0, stream>>>(
            stats, gamma + (size_t)l * 3 * H, beta + (size_t)l * 3 * H,
            st_all + (size_t)(l + 1) * 3 * 2 * H);
        unsigned short* t = xin; xin = xout; xout = t;
    }

    scale_out_kernel<<<(N_GRAPHS * 3 * 4 * H + 255) / 256, 256, 0, stream>>>(out, seg, st_all);
}

// Round 13
// 659.738 us; speedup vs baseline: 1.8234x; 1.0314x over previous
//
#include <hip/hip_runtime.h>

#define N_NODES 50000
#define N_EDGES 400000
#define N_GRAPHS 64
#define EMB 64
#define H 128
#define EPS 1e-5f

#define NCHD 8
#define CHD 6250          // N_NODES / NCHD
#define NSLICE 48

typedef __attribute__((ext_vector_type(8))) short bf16x8;
typedef __attribute__((ext_vector_type(4))) float f32x4;

__device__ __forceinline__ unsigned short f2b(float f) {
    unsigned int u = __builtin_bit_cast(unsigned int, f);
    unsigned int r = (u + 0x7fff + ((u >> 16) & 1)) >> 16;  // RNE
    return (unsigned short)r;
}

// ---------------- CSR build ----------------

__global__ void count_deg_kernel(const int* __restrict__ dst, int* __restrict__ deg) {
    int rel = blockIdx.y;
    int e = blockIdx.x * 256 + threadIdx.x;
    if (e < N_EDGES) atomicAdd(&deg[rel * N_NODES + dst[rel * N_EDGES + e]], 1);
}

// 4 elems/thread, 4096/chunk -> 13 chunks; writes row_ptr AND cur
__global__ void scan_kernel(const int* __restrict__ deg, int* __restrict__ row_ptr,
                            int* __restrict__ cur) {
    int rel = blockIdx.x;
    const int* d = deg + rel * N_NODES;
    int* rp = row_ptr + rel * (N_NODES + 1);
    int* cu = cur + rel * N_NODES;
    __shared__ int sm[1024];
    __shared__ int carry;
    if (threadIdx.x == 0) carry = 0;
    __syncthreads();
    for (int base = 0; base < N_NODES; base += 4096) {
        int i0 = base + (int)threadIdx.x * 4;
        int v[4];
        int s = 0;
#pragma unroll
        for (int k = 0; k < 4; k++) { v[k] = (i0 + k < N_NODES) ? d[i0 + k] : 0; s += v[k]; }
        sm[threadIdx.x] = s;
        __syncthreads();
        for (int off = 1; off < 1024; off <<= 1) {
            int t = (threadIdx.x >= off) ? sm[threadIdx.x - off] : 0;
            __syncthreads();
            sm[threadIdx.x] += t;
            __syncthreads();
        }
        int run = carry + sm[threadIdx.x] - s;
#pragma unroll
        for (int k = 0; k < 4; k++) {
            if (i0 + k < N_NODES) { rp[i0 + k] = run; cu[i0 + k] = run; }
            run += v[k];
        }
        __syncthreads();
        if (threadIdx.x == 1023) carry += sm[1023];
        __syncthreads();
    }
    if (threadIdx.x == 0) rp[N_NODES] = carry;
}

// dst-partitioned fill: each block owns a dst-chunk; writes land in one
// contiguous edge_src region -> full-line writebacks (was 14x amplified).
__global__ void fill_part_kernel(const int* __restrict__ src, const int* __restrict__ dst,
                                 int* __restrict__ cur, int* __restrict__ edge_src) {
    int rel = blockIdx.z;
    int lo = blockIdx.y * CHD, hi = lo + CHD;
    const int* ds = dst + (size_t)rel * N_EDGES;
    const int* ss = src + (size_t)rel * N_EDGES;
    int* cu = cur + rel * N_NODES;
    int* es = edge_src + (size_t)rel * N_EDGES;
    for (int e = blockIdx.x * 256 + threadIdx.x; e < N_EDGES; e += NSLICE * 256) {
        int dn = ds[e];
        if (dn >= lo && dn < hi) {
            int pos = atomicAdd(&cu[dn], 1);
            es[pos] = ss[e];
        }
    }
}

// sort each node's adjacency list by src (contiguous ~32B segments, L2-resident)
__global__ void sort_adj_kernel(const int* __restrict__ row_ptr, int* __restrict__ edge_src) {
    int i = blockIdx.x * 256 + threadIdx.x;
    if (i >= 3 * N_NODES) return;
    int rel = i / N_NODES, n = i - rel * N_NODES;
    const int* rp = row_ptr + rel * (N_NODES + 1);
    int* es = edge_src + rel * N_EDGES;
    int s0 = rp[n], s1 = rp[n + 1];
    for (int a = s0 + 1; a < s1; a++) {
        int key = es[a];
        int b = a - 1;
        while (b >= s0 && es[b] > key) { es[b + 1] = es[b]; b--; }
        es[b + 1] = key;
    }
}

// ---------------- Fused init: layer-1 weights + bf16 emb tables ----------------

__global__ void prep_init_kernel(const float* __restrict__ W1self, const float* __restrict__ W1neigh,
                                 unsigned short* __restrict__ Wbt1,
                                 const float* __restrict__ emb_h, const float* __restrict__ emb_p,
                                 const float* __restrict__ emb_hp,
                                 unsigned short* __restrict__ emb_bf) {
    if (blockIdx.x < 192) {
        int idx = blockIdx.x * 256 + threadIdx.x;  // 3*H*128 = 49152
        int rel = idx / (H * 128), rem = idx % (H * 128);
        int c = rem / 128, k = rem % 128;
        float v = (k < 64) ? W1self[((size_t)rel * 64 + k) * H + c]
                           : W1neigh[((size_t)rel * 64 + (k - 64)) * H + c];
        Wbt1[idx] = f2b(v);
    } else {
        int i = (blockIdx.x - 192) * 256 + threadIdx.x;
        if (i >= 3 * 257 * EMB / 8) return;
        int rel = i / (257 * EMB / 8), j = i % (257 * EMB / 8);
        const float* emb = rel == 0 ? emb_h : (rel == 1 ? emb_p : emb_hp);
        const float* e = emb + (size_t)j * 8;
        unsigned short o[8];
#pragma unroll
        for (int k = 0; k < 8; k++) o[k] = f2b(e[k]);
        *(uint4*)&emb_bf[(size_t)rel * 257 * EMB + (size_t)j * 8] = *(uint4*)o;
    }
}

// ---------------- Layer-1 aggregation via emb tables (cache-resident) ----------------

__global__ __launch_bounds__(256) void aggregate1_kernel(
        const int* __restrict__ h_idx, const int* __restrict__ p_idx,
        const int* __restrict__ hp_idx,
        const unsigned short* __restrict__ emb_bf,   // [3][257][64]
        const int* __restrict__ row_ptr, const int* __restrict__ edge_src,
        unsigned short* __restrict__ nmean) {
    const int TPN = 8;
    int rel = blockIdx.y;
    int node = blockIdx.x * 32 + threadIdx.x / TPN;
    int c8 = (threadIdx.x % TPN) * 8;
    if (node >= N_NODES) return;
    const int* idxarr = rel == 0 ? h_idx : (rel == 1 ? p_idx : hp_idx);
    const unsigned short* emb = emb_bf + (size_t)rel * 257 * EMB;
    const int* rp = row_ptr + rel * (N_NODES + 1);
    const int* es = edge_src + rel * N_EDGES;
    int s0 = rp[node], s1 = rp[node + 1];
    float acc[8];
#pragma unroll
    for (int j = 0; j < 8; j++) acc[j] = 0.f;

#define ACCUM(V)                                                                      \
    {                                                                                 \
        unsigned int w[4] = {(V).x, (V).y, (V).z, (V).w};                             \
        _Pragma("unroll") for (int j = 0; j < 4; j++) {                               \
            acc[2 * j] += __builtin_bit_cast(float, w[j] << 16);                      \
            acc[2 * j + 1] += __builtin_bit_cast(float, w[j] & 0xffff0000u);          \
        }                                                                             \
    }

    int e = s0;
    for (; e + 4 <= s1; e += 4) {
        int i0 = idxarr[es[e]], i1 = idxarr[es[e + 1]];
        int i2 = idxarr[es[e + 2]], i3 = idxarr[es[e + 3]];
        uint4 v0 = *(const uint4*)&emb[(size_t)i0 * EMB + c8];
        uint4 v1 = *(const uint4*)&emb[(size_t)i1 * EMB + c8];
        uint4 v2 = *(const uint4*)&emb[(size_t)i2 * EMB + c8];
        uint4 v3 = *(const uint4*)&emb[(size_t)i3 * EMB + c8];
        ACCUM(v0) ACCUM(v1) ACCUM(v2) ACCUM(v3)
    }
    for (; e < s1; e++) {
        uint4 v0 = *(const uint4*)&emb[(size_t)idxarr[es[e]] * EMB + c8];
        ACCUM(v0)
    }
    int deg = s1 - s0;
    float inv = 1.f / (float)max(deg, 1);
    unsigned short o[8];
#pragma unroll
    for (int j = 0; j < 8; j++)
        o[j] = (deg > 0) ? f2b(acc[j] * inv) : (unsigned short)0;
    *(uint4*)&nmean[((size_t)rel * N_NODES + node) * EMB + c8] = *(uint4*)o;
}

// ---------------- Layers 2-4 aggregation ----------------
// Long-lived blocks (96 nodes each, 6 batches of 16); src-sorted adjacency ->
// resident blocks sweep x in phase, keeping the live src window L2-sized.

template <bool FOLD>
__global__ __launch_bounds__(256) void aggregate_kernel(
        const unsigned short* __restrict__ x,      // [rel][N][128] bf16
        const int* __restrict__ row_ptr, const int* __restrict__ edge_src,
        const float* __restrict__ st,
        unsigned short* __restrict__ nmean) {
    const int TPN = 16;
    int rel = blockIdx.y;
    int c8 = (threadIdx.x % TPN) * 8;
    int nloc = threadIdx.x / TPN;               // 0..15
    const int* rp = row_ptr + rel * (N_NODES + 1);
    const int* es = edge_src + rel * N_EDGES;
    const unsigned short* xr = x + (size_t)rel * N_NODES * H;

    float sj[8], tj[8];
    if (FOLD) {
#pragma unroll
        for (int j = 0; j < 8; j++) {
            sj[j] = st[rel * 2 * H + c8 + j];
            tj[j] = st[rel * 2 * H + H + c8 + j];
        }
    }

#pragma unroll
    for (int batch = 0; batch < 6; batch++) {
        int node = blockIdx.x * 96 + batch * 16 + nloc;
        if (node >= N_NODES) continue;
        int s0 = rp[node], s1 = rp[node + 1];
        float acc[8];
#pragma unroll
        for (int j = 0; j < 8; j++) acc[j] = 0.f;
        int e = s0;
        for (; e + 4 <= s1; e += 4) {
            int i0 = es[e], i1 = es[e + 1], i2 = es[e + 2], i3 = es[e + 3];
            uint4 v0 = *(const uint4*)&xr[(size_t)i0 * H + c8];
            uint4 v1 = *(const uint4*)&xr[(size_t)i1 * H + c8];
            uint4 v2 = *(const uint4*)&xr[(size_t)i2 * H + c8];
            uint4 v3 = *(const uint4*)&xr[(size_t)i3 * H + c8];
            ACCUM(v0) ACCUM(v1) ACCUM(v2) ACCUM(v3)
        }
        for (; e < s1; e++) {
            uint4 v0 = *(const uint4*)&xr[(size_t)es[e] * H + c8];
            ACCUM(v0)
        }
        int deg = s1 - s0;
        float inv = 1.f / (float)max(deg, 1);
        unsigned short o[8];
#pragma unroll
        for (int j = 0; j < 8; j++) {
            float m = acc[j] * inv;
            if (FOLD) m = sj[j] * m + tj[j];
            o[j] = (deg > 0) ? f2b(m) : (unsigned short)0;
        }
        *(uint4*)&nmean[((size_t)rel * N_NODES + node) * H + c8] = *(uint4*)o;
    }
#undef ACCUM
}

// ---- MFMA GEMM (single-buffer LDS, proven config): hp = PReLU([x | nmean] @ Wbt^T + bias);
//      fp32 col stats; per-graph readout sums fused into epilogue.
//      G1: self-half staged from cache-resident emb_bf via idx (layer 1). ----

template <int KX, bool G1>
__global__ __launch_bounds__(256) void gemm_kernel(
        const unsigned short* __restrict__ x,
        const unsigned short* __restrict__ nmean,
        const unsigned short* __restrict__ Wbt,
        const float* __restrict__ bias,
        const float* __restrict__ alpha,
        unsigned short* __restrict__ out,
        float* __restrict__ stats,
        const int* __restrict__ seg_all,
        float* __restrict__ gout,
        int layer,
        const unsigned short* __restrict__ embt,
        const int* __restrict__ h_idx, const int* __restrict__ p_idx,
        const int* __restrict__ hp_idx) {
    const int KTOT = 2 * KX;
    int rel = blockIdx.y;
    int row0 = blockIdx.x * 128;
    const unsigned short* xr = x + (size_t)rel * N_NODES * KX;
    const unsigned short* nm = nmean + (size_t)rel * N_NODES * KX;
    const unsigned short* W = Wbt + (size_t)rel * H * KTOT;
    unsigned short* o = out + (size_t)rel * N_NODES * H;

    __shared__ __align__(16) short At[128][40];
    __shared__ __align__(16) short Bt[128][40];

    int tid = threadIdx.x;
    int lane = tid & 63;
    int wave = tid >> 6;
    int wr = wave >> 1, wc = wave & 1;
    int l15 = lane & 15;
    int koff = (lane >> 4) * 8;

    f32x4 acc[4][4];
#pragma unroll
    for (int m = 0; m < 4; m++)
#pragma unroll
        for (int n = 0; n < 4; n++) acc[m][n] = (f32x4){0.f, 0.f, 0.f, 0.f};

    int seg = tid & 3;
    int rloc = tid >> 2;

    int nid0 = 0, nid1 = 0;
    if (G1) {
        const int* idxarr = rel == 0 ? h_idx : (rel == 1 ? p_idx : hp_idx);
        if (row0 + rloc < N_NODES) nid0 = idxarr[row0 + rloc];
        if (row0 + 64 + rloc < N_NODES) nid1 = idxarr[row0 + 64 + rloc];
    }
    const unsigned short* et = G1 ? (embt + (size_t)rel * 257 * EMB) : nullptr;

    for (int kc = 0; kc < KTOT; kc += 32) {
        const bool selfh = kc < KX;
        const unsigned short* Asrc = selfh ? xr : nm;
        int kb = selfh ? kc : kc - KX;
#pragma unroll
        for (int i = 0; i < 2; i++) {
            int r = i * 64 + rloc;
            int gr = row0 + r;
            uint4 v = make_uint4(0u, 0u, 0u, 0u);
            if (gr < N_NODES) {
                if (G1 && selfh) {
                    int nid = i ? nid1 : nid0;
                    v = *(const uint4*)&et[(size_t)nid * EMB + kb + seg * 8];
                } else {
                    v = *(const uint4*)&Asrc[(size_t)gr * KX + kb + seg * 8];
                }
            }
            *(uint4*)&At[r][seg * 8] = v;
        }
#pragma unroll
        for (int i = 0; i < 2; i++) {
            int c = i * 64 + rloc;
            *(uint4*)&Bt[c][seg * 8] = *(const uint4*)&W[(size_t)c * KTOT + kc + seg * 8];
        }
        __syncthreads();
        bf16x8 a[4], b[4];
#pragma unroll
        for (int m = 0; m < 4; m++) a[m] = *(const bf16x8*)&At[wr * 64 + m * 16 + l15][koff];
#pragma unroll
        for (int n = 0; n < 4; n++) b[n] = *(const bf16x8*)&Bt[wc * 64 + n * 16 + l15][koff];
#pragma unroll
        for (int m = 0; m < 4; m++)
#pragma unroll
            for (int n = 0; n < 4; n++)
                acc[m][n] = __builtin_amdgcn_mfma_f32_16x16x32_bf16(a[m], b[n], acc[m][n], 0, 0, 0);
        __syncthreads();
    }

    float bs[4], as_[4];
#pragma unroll
    for (int n = 0; n < 4; n++) {
        int col = wc * 64 + n * 16 + l15;
        bs[n] = bias[rel * H + col];
        as_[n] = alpha[rel * H + col];
    }
    const int* sg = seg_all + rel * N_NODES;
    float csum[4] = {0.f, 0.f, 0.f, 0.f}, cssq[4] = {0.f, 0.f, 0.f, 0.f};
    int curg = -1;
    float run[4] = {0.f, 0.f, 0.f, 0.f};
    int rbase = row0 + wr * 64 + (lane >> 4) * 4;
#pragma unroll
    for (int m = 0; m < 4; m++) {
#pragma unroll
        for (int j = 0; j < 4; j++) {
            int r = rbase + m * 16 + j;
            if (r >= N_NODES) continue;
            int g = sg[r];
            if (g != curg) {
                if (curg >= 0) {
                    float* ob = gout + (size_t)curg * (3 * 4 * H) + rel * (4 * H) + layer * H + wc * 64 + l15;
#pragma unroll
                    for (int n = 0; n < 4; n++) { atomicAdd(ob + n * 16, run[n]); run[n] = 0.f; }
                }
                curg = g;
            }
#pragma unroll
            for (int n = 0; n < 4; n++) {
                float v = acc[m][n][j] + bs[n];
                v = v > 0.f ? v : as_[n] * v;
                o[(size_t)r * H + wc * 64 + n * 16 + l15] = f2b(v);
                csum[n] += v;
                cssq[n] += v * v;
                run[n] += v;
            }
        }
    }
    if (curg >= 0) {
        float* ob = gout + (size_t)curg * (3 * 4 * H) + rel * (4 * H) + layer * H + wc * 64 + l15;
#pragma unroll
        for (int n = 0; n < 4; n++) atomicAdd(ob + n * 16, run[n]);
    }
    __syncthreads();
    float* smS = (float*)&At[0][0];
    float* smQ = (float*)&Bt[0][0];
    int contrib = wr * 4 + (lane >> 4);
#pragma unroll
    for (int n = 0; n < 4; n++) {
        int col = wc * 64 + n * 16 + l15;
        smS[col * 8 + contrib] = csum[n];
        smQ[col * 8 + contrib] = cssq[n];
    }
    __syncthreads();
    if (tid < 128) {
        float s = 0.f, q = 0.f;
#pragma unroll
        for (int i = 0; i < 8; i++) { s += smS[tid * 8 + i]; q += smQ[tid * 8 + i]; }
        atomicAdd(&stats[rel * 256 + tid], s);
        atomicAdd(&stats[rel * 256 + 128 + tid], q);
    }
}

// ---------------- BN stats -> affine (s,t); self-zero stats ----------------

__global__ void finalize_kernel(float* __restrict__ stats,
                                const float* __restrict__ gamma, const float* __restrict__ beta,
                                float* __restrict__ st) {
    int rel = blockIdx.x, c = threadIdx.x;
    const float invN = 1.f / N_NODES;
    float mu = stats[rel * 256 + c] * invN;
    float var = stats[rel * 256 + 128 + c] * invN - mu * mu;
    float s = gamma[rel * H + c] * rsqrtf(var + EPS);
    st[rel * 2 * H + c] = s;
    st[rel * 2 * H + H + c] = beta[rel * H + c] - mu * s;
    stats[rel * 256 + c] = 0.f;
    stats[rel * 256 + 128 + c] = 0.f;
}

// ---------------- Weight prep (layers 2-4) ----------------

__global__ void prep_kernel(const float* __restrict__ Wself, const float* __restrict__ Wneigh,
                            const float* __restrict__ b, const float* __restrict__ st,
                            unsigned short* __restrict__ Wbt, float* __restrict__ biasp) {
    if (blockIdx.x < 384) {
        int idx = blockIdx.x * 256 + threadIdx.x;
        int rel = idx / (H * 256), rem = idx % (H * 256);
        int c = rem / 256, k = rem % 256;
        float v;
        if (k < 128) v = st[rel * 2 * H + k] * Wself[((size_t)rel * H + k) * H + c];
        else         v = Wneigh[((size_t)rel * H + (k - 128)) * H + c];
        Wbt[idx] = f2b(v);
    } else if (threadIdx.x < H) {
        int rel = blockIdx.x - 384, c = threadIdx.x;
        const float* t = st + rel * 2 * H + H;
        float s = b[rel * H + c];
        for (int k = 0; k < H; k++) s += t[k] * Wself[((size_t)rel * H + k) * H + c];
        biasp[rel * H + c] = s;
    }
}

// ---------------- Final: mean + BN affine ----------------

__global__ void scale_out_kernel(float* __restrict__ out, const int* __restrict__ seg,
                                 const float* __restrict__ st_all) {
    int i = blockIdx.x * 256 + threadIdx.x;
    if (i >= N_GRAPHS * 3 * 4 * H) return;
    int g = i / (3 * 4 * H), k = i % (3 * 4 * H);
    int rel = k / (4 * H), rem = k % (4 * H), layer = rem / H, c = rem % H;
    const int* sg = seg + rel * N_NODES;
    int lo = 0, hi = N_NODES;
    while (lo < hi) { int m = (lo + hi) >> 1; if (sg[m] < g) lo = m + 1; else hi = m; }
    int start = lo;
    hi = N_NODES;
    while (lo < hi) { int m = (lo + hi) >> 1; if (sg[m] <= g) lo = m + 1; else hi = m; }
    int cnt = lo - start;
    float mean = out[i] / (float)max(cnt, 1);
    const float* st = st_all + ((size_t)layer * 3 + rel) * 2 * H;
    out[i] = st[c] * mean + st[H + c];
}

// ---------------- Orchestration ----------------

extern "C" void kernel_launch(void* const* d_in, const int* in_sizes, int n_in,
                              void* d_out, int out_size, void* d_ws, size_t ws_size,
                              hipStream_t stream) {
    const int* h_idx = (const int*)d_in[0];
    const int* p_idx = (const int*)d_in[1];
    const int* hp_idx = (const int*)d_in[2];
    const int* src = (const int*)d_in[3];
    const int* dst = (const int*)d_in[4];
    const int* seg = (const int*)d_in[5];
    const float* emb_h = (const float*)d_in[6];
    const float* emb_p = (const float*)d_in[7];
    const float* emb_hp = (const float*)d_in[8];
    const float* W1_self = (const float*)d_in[9];
    const float* W1_neigh = (const float*)d_in[10];
    const float* b1 = (const float*)d_in[11];
    const float* a1 = (const float*)d_in[12];
    const float* gamma1 = (const float*)d_in[13];
    const float* beta1 = (const float*)d_in[14];
    const float* W_self = (const float*)d_in[15];
    const float* W_neigh = (const float*)d_in[16];
    const float* b = (const float*)d_in[17];
    const float* a = (const float*)d_in[18];
    const float* gamma = (const float*)d_in[19];
    const float* beta = (const float*)d_in[20];
    float* out = (float*)d_out;

    // workspace
    char* p = (char*)d_ws;
    unsigned short* hpA = (unsigned short*)p; p += (size_t)3 * N_NODES * H * 2;    // 38.4 MB
    unsigned short* hpB = (unsigned short*)p; p += (size_t)3 * N_NODES * H * 2;    // 38.4 MB
    unsigned short* Wbt1 = (unsigned short*)p; p += (size_t)3 * H * 128 * 2;
    unsigned short* Wbt = (unsigned short*)p; p += (size_t)3 * H * 256 * 2;
    unsigned short* emb_bf = (unsigned short*)p; p += (size_t)3 * 257 * EMB * 2;
    float* biasp = (float*)p; p += 3 * H * sizeof(float);
    float* st_all = (float*)p; p += 4 * 3 * 2 * H * sizeof(float);
    float* stats = (float*)p; p += 3 * 256 * sizeof(float);
    int* deg = (int*)p; p += (size_t)3 * N_NODES * 4;
    int* row_ptr = (int*)p; p += (size_t)3 * (N_NODES + 1) * 4;
    int* cur = (int*)p; p += (size_t)3 * N_NODES * 4;
    int* edge_src = (int*)p; p += (size_t)3 * N_EDGES * 4;

    hipMemsetAsync(out, 0, (size_t)N_GRAPHS * 3 * 4 * H * sizeof(float), stream);
    hipMemsetAsync(stats, 0, 3 * 256 * 4, stream);

    // CSR build + per-node src-sort
    hipMemsetAsync(deg, 0, (size_t)3 * N_NODES * 4, stream);
    dim3 eb((N_EDGES + 255) / 256, 3);
    count_deg_kernel<<<eb, 256, 0, stream>>>(dst, deg);
    scan_kernel<<<3, 1024, 0, stream>>>(deg, row_ptr, cur);
    fill_part_kernel<<<dim3(NSLICE, NCHD, 3), 256, 0, stream>>>(src, dst, cur, edge_src);
    sort_adj_kernel<<<(3 * N_NODES + 255) / 256, 256, 0, stream>>>(row_ptr, edge_src);

    prep_init_kernel<<<217, 256, 0, stream>>>(W1_self, W1_neigh, Wbt1,
                                              emb_h, emb_p, emb_hp, emb_bf);

    dim3 gemm_grid((N_NODES + 127) / 128, 3);
    dim3 agg_grid((N_NODES + 95) / 96, 3);

    // ---- layer 1 (K = 64; nmean ld=64 in hpB via emb-table gather; out hpA) ----
    aggregate1_kernel<<<dim3((N_NODES + 31) / 32, 3), 256, 0, stream>>>(
        h_idx, p_idx, hp_idx, emb_bf, row_ptr, edge_src, hpB);
    gemm_kernel<64, true><<<gemm_grid, 256, 0, stream>>>(
        emb_bf /*unused*/, hpB, Wbt1, b1, a1, hpA, stats, seg, out, 0,
        emb_bf, h_idx, p_idx, hp_idx);
    finalize_kernel<<<3, H, 0, stream>>>(stats, gamma1, beta1, st_all);

    // ---- layers 2-4 (K = 128; out aliases nmean) ----
    unsigned short* xin = hpA;
    unsigned short* xout = hpB;
    for (int l = 0; l < 3; l++) {
        const float* st_prev = st_all + (size_t)l * 3 * 2 * H;
        prep_kernel<<<387, 256, 0, stream>>>(
            W_self + (size_t)l * 3 * H * H, W_neigh + (size_t)l * 3 * H * H,
            b + (size_t)l * 3 * H, st_prev, Wbt, biasp);
        aggregate_kernel<true><<<agg_grid, 256, 0, stream>>>(
            xin, row_ptr, edge_src, st_prev, xout);
        gemm_kernel<128, false><<<gemm_grid, 256, 0, stream>>>(
            xin, xout, Wbt, biasp, a + (size_t)l * 3 * H, xout, stats, seg, out, l + 1,
            nullptr, nullptr, nullptr, nullptr);
        finalize_kernel<<<3, H, 0, stream>>>(
            stats, gamma + (size_t)l * 3 * H, beta + (size_t)l * 3 * H,
            st_all + (size_t)(l + 1) * 3 * 2 * H);
        unsigned short* t = xin; xin = xout; xout = t;
    }

    scale_out_kernel<<<(N_GRAPHS * 3 * 4 * H + 255) / 256, 256, 0, stream>>>(out, seg, st_all);
}

// Round 14
// 651.236 us; speedup vs baseline: 1.8473x; 1.0131x over previous
//
#include <hip/hip_runtime.h>

#define N_NODES 50000
#define N_EDGES 400000
#define N_GRAPHS 64
#define EMB 64
#define H 128
#define EPS 1e-5f

#define NCH2 49            // dst chunks of 1024 nodes (edge region ~32 KB each)
#define NSLA 48            // partition slices

typedef __attribute__((ext_vector_type(8))) short bf16x8;
typedef __attribute__((ext_vector_type(4))) float f32x4;

__device__ __forceinline__ unsigned short f2b(float f) {
    unsigned int u = __builtin_bit_cast(unsigned int, f);
    unsigned int r = (u + 0x7fff + ((u >> 16) & 1)) >> 16;  // RNE
    return (unsigned short)r;
}

// ---------------- CSR build ----------------

__global__ void count_deg_kernel(const int* __restrict__ dst, int* __restrict__ deg) {
    int rel = blockIdx.y;
    int e = blockIdx.x * 256 + threadIdx.x;
    if (e < N_EDGES) atomicAdd(&deg[rel * N_NODES + dst[rel * N_EDGES + e]], 1);
}

// 4 elems/thread; writes row_ptr, cur, and per-chunk cursors gcur
__global__ void scan_kernel(const int* __restrict__ deg, int* __restrict__ row_ptr,
                            int* __restrict__ cur, int* __restrict__ gcur) {
    int rel = blockIdx.x;
    const int* d = deg + rel * N_NODES;
    int* rp = row_ptr + rel * (N_NODES + 1);
    int* cu = cur + rel * N_NODES;
    __shared__ int sm[1024];
    __shared__ int carry;
    if (threadIdx.x == 0) carry = 0;
    __syncthreads();
    for (int base = 0; base < N_NODES; base += 4096) {
        int i0 = base + (int)threadIdx.x * 4;
        int v[4];
        int s = 0;
#pragma unroll
        for (int k = 0; k < 4; k++) { v[k] = (i0 + k < N_NODES) ? d[i0 + k] : 0; s += v[k]; }
        sm[threadIdx.x] = s;
        __syncthreads();
        for (int off = 1; off < 1024; off <<= 1) {
            int t = (threadIdx.x >= off) ? sm[threadIdx.x - off] : 0;
            __syncthreads();
            sm[threadIdx.x] += t;
            __syncthreads();
        }
        int run = carry + sm[threadIdx.x] - s;
#pragma unroll
        for (int k = 0; k < 4; k++) {
            int i = i0 + k;
            if (i < N_NODES) {
                rp[i] = run;
                cu[i] = run;
                if ((i & 1023) == 0) gcur[rel * NCH2 + (i >> 10)] = run;
            }
            run += v[k];
        }
        __syncthreads();
        if (threadIdx.x == 1023) carry += sm[1023];
        __syncthreads();
    }
    if (threadIdx.x == 0) rp[N_NODES] = carry;
}

// Phase A: partition edges into dst-chunk-major staging buffer (contiguous runs)
__global__ __launch_bounds__(256) void partA_kernel(
        const int* __restrict__ src, const int* __restrict__ dst,
        int* __restrict__ gcur, unsigned long long* __restrict__ chunkbuf) {
    int rel = blockIdx.y;
    const int* ds = dst + (size_t)rel * N_EDGES;
    const int* ss = src + (size_t)rel * N_EDGES;
    unsigned long long* cb = chunkbuf + (size_t)rel * N_EDGES;
    __shared__ int cnt[NCH2];
    __shared__ int lcur[NCH2];
    int tid = threadIdx.x;
    if (tid < NCH2) cnt[tid] = 0;
    __syncthreads();
    for (int e = blockIdx.x * 256 + tid; e < N_EDGES; e += NSLA * 256)
        atomicAdd(&cnt[ds[e] >> 10], 1);
    __syncthreads();
    if (tid < NCH2) lcur[tid] = atomicAdd(&gcur[rel * NCH2 + tid], cnt[tid]);
    __syncthreads();
    for (int e = blockIdx.x * 256 + tid; e < N_EDGES; e += NSLA * 256) {
        int dn = ds[e], sn = ss[e];
        int idx = atomicAdd(&lcur[dn >> 10], 1);
        cb[idx] = ((unsigned long long)(unsigned)sn << 32) | (unsigned)dn;
    }
}

// Phase B: each chunk's region placed by 2 blocks (region ~32 KB -> local lines)
__global__ __launch_bounds__(256) void fillB_kernel(
        const int* __restrict__ row_ptr, const unsigned long long* __restrict__ chunkbuf,
        int* __restrict__ cur, int* __restrict__ edge_src) {
    int rel = blockIdx.y;
    int c = blockIdx.x >> 1, half = blockIdx.x & 1;
    const int* rp = row_ptr + rel * (N_NODES + 1);
    int lo = rp[c << 10];
    int hiN = min((c + 1) << 10, N_NODES);
    int hi = rp[hiN];
    const unsigned long long* cb = chunkbuf + (size_t)rel * N_EDGES;
    int* cu = cur + rel * N_NODES;
    int* es = edge_src + (size_t)rel * N_EDGES;
    for (int i = lo + half + 2 * (int)threadIdx.x; i < hi; i += 2 * 256) {
        unsigned long long pr = cb[i];
        int dn = (int)(pr & 0xffffffffu);
        int sn = (int)(pr >> 32);
        int pos = atomicAdd(&cu[dn], 1);
        es[pos] = sn;
    }
}

// sort each node's adjacency list by src (contiguous ~32B segments, L2-resident)
__global__ void sort_adj_kernel(const int* __restrict__ row_ptr, int* __restrict__ edge_src) {
    int i = blockIdx.x * 256 + threadIdx.x;
    if (i >= 3 * N_NODES) return;
    int rel = i / N_NODES, n = i - rel * N_NODES;
    const int* rp = row_ptr + rel * (N_NODES + 1);
    int* es = edge_src + rel * N_EDGES;
    int s0 = rp[n], s1 = rp[n + 1];
    for (int a = s0 + 1; a < s1; a++) {
        int key = es[a];
        int b = a - 1;
        while (b >= s0 && es[b] > key) { es[b + 1] = es[b]; b--; }
        es[b + 1] = key;
    }
}

// ---------------- Fused init: layer-1 weights + bf16 emb tables ----------------

__global__ void prep_init_kernel(const float* __restrict__ W1self, const float* __restrict__ W1neigh,
                                 unsigned short* __restrict__ Wbt1,
                                 const float* __restrict__ emb_h, const float* __restrict__ emb_p,
                                 const float* __restrict__ emb_hp,
                                 unsigned short* __restrict__ emb_bf) {
    if (blockIdx.x < 192) {
        int idx = blockIdx.x * 256 + threadIdx.x;  // 3*H*128 = 49152
        int rel = idx / (H * 128), rem = idx % (H * 128);
        int c = rem / 128, k = rem % 128;
        float v = (k < 64) ? W1self[((size_t)rel * 64 + k) * H + c]
                           : W1neigh[((size_t)rel * 64 + (k - 64)) * H + c];
        Wbt1[idx] = f2b(v);
    } else {
        int i = (blockIdx.x - 192) * 256 + threadIdx.x;
        if (i >= 3 * 257 * EMB / 8) return;
        int rel = i / (257 * EMB / 8), j = i % (257 * EMB / 8);
        const float* emb = rel == 0 ? emb_h : (rel == 1 ? emb_p : emb_hp);
        const float* e = emb + (size_t)j * 8;
        unsigned short o[8];
#pragma unroll
        for (int k = 0; k < 8; k++) o[k] = f2b(e[k]);
        *(uint4*)&emb_bf[(size_t)rel * 257 * EMB + (size_t)j * 8] = *(uint4*)o;
    }
}

// ---------------- Layer-1 aggregation via emb tables (cache-resident) ----------------

__global__ __launch_bounds__(256) void aggregate1_kernel(
        const int* __restrict__ h_idx, const int* __restrict__ p_idx,
        const int* __restrict__ hp_idx,
        const unsigned short* __restrict__ emb_bf,   // [3][257][64]
        const int* __restrict__ row_ptr, const int* __restrict__ edge_src,
        unsigned short* __restrict__ nmean) {
    const int TPN = 8;
    int rel = blockIdx.y;
    int node = blockIdx.x * 32 + threadIdx.x / TPN;
    int c8 = (threadIdx.x % TPN) * 8;
    if (node >= N_NODES) return;
    const int* idxarr = rel == 0 ? h_idx : (rel == 1 ? p_idx : hp_idx);
    const unsigned short* emb = emb_bf + (size_t)rel * 257 * EMB;
    const int* rp = row_ptr + rel * (N_NODES + 1);
    const int* es = edge_src + rel * N_EDGES;
    int s0 = rp[node], s1 = rp[node + 1];
    float acc[8];
#pragma unroll
    for (int j = 0; j < 8; j++) acc[j] = 0.f;

#define ACCUM(V)                                                                      \
    {                                                                                 \
        unsigned int w[4] = {(V).x, (V).y, (V).z, (V).w};                             \
        _Pragma("unroll") for (int j = 0; j < 4; j++) {                               \
            acc[2 * j] += __builtin_bit_cast(float, w[j] << 16);                      \
            acc[2 * j + 1] += __builtin_bit_cast(float, w[j] & 0xffff0000u);          \
        }                                                                             \
    }

    int e = s0;
    for (; e + 4 <= s1; e += 4) {
        int i0 = idxarr[es[e]], i1 = idxarr[es[e + 1]];
        int i2 = idxarr[es[e + 2]], i3 = idxarr[es[e + 3]];
        uint4 v0 = *(const uint4*)&emb[(size_t)i0 * EMB + c8];
        uint4 v1 = *(const uint4*)&emb[(size_t)i1 * EMB + c8];
        uint4 v2 = *(const uint4*)&emb[(size_t)i2 * EMB + c8];
        uint4 v3 = *(const uint4*)&emb[(size_t)i3 * EMB + c8];
        ACCUM(v0) ACCUM(v1) ACCUM(v2) ACCUM(v3)
    }
    for (; e < s1; e++) {
        uint4 v0 = *(const uint4*)&emb[(size_t)idxarr[es[e]] * EMB + c8];
        ACCUM(v0)
    }
    int deg = s1 - s0;
    float inv = 1.f / (float)max(deg, 1);
    unsigned short o[8];
#pragma unroll
    for (int j = 0; j < 8; j++)
        o[j] = (deg > 0) ? f2b(acc[j] * inv) : (unsigned short)0;
    *(uint4*)&nmean[((size_t)rel * N_NODES + node) * EMB + c8] = *(uint4*)o;
}

// ---------------- Layers 2-4 aggregation ----------------

template <bool FOLD>
__global__ __launch_bounds__(256) void aggregate_kernel(
        const unsigned short* __restrict__ x,      // [rel][N][128] bf16
        const int* __restrict__ row_ptr, const int* __restrict__ edge_src,
        const float* __restrict__ st,
        unsigned short* __restrict__ nmean) {
    const int TPN = 16;
    int rel = blockIdx.y;
    int c8 = (threadIdx.x % TPN) * 8;
    int nloc = threadIdx.x / TPN;               // 0..15
    const int* rp = row_ptr + rel * (N_NODES + 1);
    const int* es = edge_src + rel * N_EDGES;
    const unsigned short* xr = x + (size_t)rel * N_NODES * H;

    float sj[8], tj[8];
    if (FOLD) {
#pragma unroll
        for (int j = 0; j < 8; j++) {
            sj[j] = st[rel * 2 * H + c8 + j];
            tj[j] = st[rel * 2 * H + H + c8 + j];
        }
    }

#pragma unroll
    for (int batch = 0; batch < 6; batch++) {
        int node = blockIdx.x * 96 + batch * 16 + nloc;
        if (node >= N_NODES) continue;
        int s0 = rp[node], s1 = rp[node + 1];
        float acc[8];
#pragma unroll
        for (int j = 0; j < 8; j++) acc[j] = 0.f;
        int e = s0;
        for (; e + 4 <= s1; e += 4) {
            int i0 = es[e], i1 = es[e + 1], i2 = es[e + 2], i3 = es[e + 3];
            uint4 v0 = *(const uint4*)&xr[(size_t)i0 * H + c8];
            uint4 v1 = *(const uint4*)&xr[(size_t)i1 * H + c8];
            uint4 v2 = *(const uint4*)&xr[(size_t)i2 * H + c8];
            uint4 v3 = *(const uint4*)&xr[(size_t)i3 * H + c8];
            ACCUM(v0) ACCUM(v1) ACCUM(v2) ACCUM(v3)
        }
        for (; e < s1; e++) {
            uint4 v0 = *(const uint4*)&xr[(size_t)es[e] * H + c8];
            ACCUM(v0)
        }
        int deg = s1 - s0;
        float inv = 1.f / (float)max(deg, 1);
        unsigned short o[8];
#pragma unroll
        for (int j = 0; j < 8; j++) {
            float m = acc[j] * inv;
            if (FOLD) m = sj[j] * m + tj[j];
            o[j] = (deg > 0) ? f2b(m) : (unsigned short)0;
        }
        *(uint4*)&nmean[((size_t)rel * N_NODES + node) * H + c8] = *(uint4*)o;
    }
#undef ACCUM
}

// ---- MFMA GEMM: hp = PReLU([x | nmean] @ Wbt^T + bias); fp32 col stats;
//      per-graph readout fused; STORE=false skips the bf16 hp write (last layer). ----

template <int KX, bool G1, bool STORE>
__global__ __launch_bounds__(256) void gemm_kernel(
        const unsigned short* __restrict__ x,
        const unsigned short* __restrict__ nmean,
        const unsigned short* __restrict__ Wbt,
        const float* __restrict__ bias,
        const float* __restrict__ alpha,
        unsigned short* __restrict__ out,
        float* __restrict__ stats,
        const int* __restrict__ seg_all,
        float* __restrict__ gout,
        int layer,
        const unsigned short* __restrict__ embt,
        const int* __restrict__ h_idx, const int* __restrict__ p_idx,
        const int* __restrict__ hp_idx) {
    const int KTOT = 2 * KX;
    int rel = blockIdx.y;
    int row0 = blockIdx.x * 128;
    const unsigned short* xr = x + (size_t)rel * N_NODES * KX;
    const unsigned short* nm = nmean + (size_t)rel * N_NODES * KX;
    const unsigned short* W = Wbt + (size_t)rel * H * KTOT;
    unsigned short* o = out + (size_t)rel * N_NODES * H;

    __shared__ __align__(16) short At[128][40];
    __shared__ __align__(16) short Bt[128][40];

    int tid = threadIdx.x;
    int lane = tid & 63;
    int wave = tid >> 6;
    int wr = wave >> 1, wc = wave & 1;
    int l15 = lane & 15;
    int koff = (lane >> 4) * 8;

    f32x4 acc[4][4];
#pragma unroll
    for (int m = 0; m < 4; m++)
#pragma unroll
        for (int n = 0; n < 4; n++) acc[m][n] = (f32x4){0.f, 0.f, 0.f, 0.f};

    int seg = tid & 3;
    int rloc = tid >> 2;

    int nid0 = 0, nid1 = 0;
    if (G1) {
        const int* idxarr = rel == 0 ? h_idx : (rel == 1 ? p_idx : hp_idx);
        if (row0 + rloc < N_NODES) nid0 = idxarr[row0 + rloc];
        if (row0 + 64 + rloc < N_NODES) nid1 = idxarr[row0 + 64 + rloc];
    }
    const unsigned short* et = G1 ? (embt + (size_t)rel * 257 * EMB) : nullptr;

    for (int kc = 0; kc < KTOT; kc += 32) {
        const bool selfh = kc < KX;
        const unsigned short* Asrc = selfh ? xr : nm;
        int kb = selfh ? kc : kc - KX;
#pragma unroll
        for (int i = 0; i < 2; i++) {
            int r = i * 64 + rloc;
            int gr = row0 + r;
            uint4 v = make_uint4(0u, 0u, 0u, 0u);
            if (gr < N_NODES) {
                if (G1 && selfh) {
                    int nid = i ? nid1 : nid0;
                    v = *(const uint4*)&et[(size_t)nid * EMB + kb + seg * 8];
                } else {
                    v = *(const uint4*)&Asrc[(size_t)gr * KX + kb + seg * 8];
                }
            }
            *(uint4*)&At[r][seg * 8] = v;
        }
#pragma unroll
        for (int i = 0; i < 2; i++) {
            int c = i * 64 + rloc;
            *(uint4*)&Bt[c][seg * 8] = *(const uint4*)&W[(size_t)c * KTOT + kc + seg * 8];
        }
        __syncthreads();
        bf16x8 a[4], b[4];
#pragma unroll
        for (int m = 0; m < 4; m++) a[m] = *(const bf16x8*)&At[wr * 64 + m * 16 + l15][koff];
#pragma unroll
        for (int n = 0; n < 4; n++) b[n] = *(const bf16x8*)&Bt[wc * 64 + n * 16 + l15][koff];
#pragma unroll
        for (int m = 0; m < 4; m++)
#pragma unroll
            for (int n = 0; n < 4; n++)
                acc[m][n] = __builtin_amdgcn_mfma_f32_16x16x32_bf16(a[m], b[n], acc[m][n], 0, 0, 0);
        __syncthreads();
    }

    float bs[4], as_[4];
#pragma unroll
    for (int n = 0; n < 4; n++) {
        int col = wc * 64 + n * 16 + l15;
        bs[n] = bias[rel * H + col];
        as_[n] = alpha[rel * H + col];
    }
    const int* sg = seg_all + rel * N_NODES;
    float csum[4] = {0.f, 0.f, 0.f, 0.f}, cssq[4] = {0.f, 0.f, 0.f, 0.f};
    int curg = -1;
    float run[4] = {0.f, 0.f, 0.f, 0.f};
    int rbase = row0 + wr * 64 + (lane >> 4) * 4;
#pragma unroll
    for (int m = 0; m < 4; m++) {
#pragma unroll
        for (int j = 0; j < 4; j++) {
            int r = rbase + m * 16 + j;
            if (r >= N_NODES) continue;
            int g = sg[r];
            if (g != curg) {
                if (curg >= 0) {
                    float* ob = gout + (size_t)curg * (3 * 4 * H) + rel * (4 * H) + layer * H + wc * 64 + l15;
#pragma unroll
                    for (int n = 0; n < 4; n++) { atomicAdd(ob + n * 16, run[n]); run[n] = 0.f; }
                }
                curg = g;
            }
#pragma unroll
            for (int n = 0; n < 4; n++) {
                float v = acc[m][n][j] + bs[n];
                v = v > 0.f ? v : as_[n] * v;
                if (STORE) o[(size_t)r * H + wc * 64 + n * 16 + l15] = f2b(v);
                csum[n] += v;
                cssq[n] += v * v;
                run[n] += v;
            }
        }
    }
    if (curg >= 0) {
        float* ob = gout + (size_t)curg * (3 * 4 * H) + rel * (4 * H) + layer * H + wc * 64 + l15;
#pragma unroll
        for (int n = 0; n < 4; n++) atomicAdd(ob + n * 16, run[n]);
    }
    __syncthreads();
    float* smS = (float*)&At[0][0];
    float* smQ = (float*)&Bt[0][0];
    int contrib = wr * 4 + (lane >> 4);
#pragma unroll
    for (int n = 0; n < 4; n++) {
        int col = wc * 64 + n * 16 + l15;
        smS[col * 8 + contrib] = csum[n];
        smQ[col * 8 + contrib] = cssq[n];
    }
    __syncthreads();
    if (tid < 128) {
        float s = 0.f, q = 0.f;
#pragma unroll
        for (int i = 0; i < 8; i++) { s += smS[tid * 8 + i]; q += smQ[tid * 8 + i]; }
        atomicAdd(&stats[rel * 256 + tid], s);
        atomicAdd(&stats[rel * 256 + 128 + tid], q);
    }
}

// ---------------- BN stats -> affine (s,t); self-zero stats ----------------

__global__ void finalize_kernel(float* __restrict__ stats,
                                const float* __restrict__ gamma, const float* __restrict__ beta,
                                float* __restrict__ st) {
    int rel = blockIdx.x, c = threadIdx.x;
    const float invN = 1.f / N_NODES;
    float mu = stats[rel * 256 + c] * invN;
    float var = stats[rel * 256 + 128 + c] * invN - mu * mu;
    float s = gamma[rel * H + c] * rsqrtf(var + EPS);
    st[rel * 2 * H + c] = s;
    st[rel * 2 * H + H + c] = beta[rel * H + c] - mu * s;
    stats[rel * 256 + c] = 0.f;
    stats[rel * 256 + 128 + c] = 0.f;
}

// ---------------- Weight prep (layers 2-4) ----------------

__global__ void prep_kernel(const float* __restrict__ Wself, const float* __restrict__ Wneigh,
                            const float* __restrict__ b, const float* __restrict__ st,
                            unsigned short* __restrict__ Wbt, float* __restrict__ biasp) {
    if (blockIdx.x < 384) {
        int idx = blockIdx.x * 256 + threadIdx.x;
        int rel = idx / (H * 256), rem = idx % (H * 256);
        int c = rem / 256, k = rem % 256;
        float v;
        if (k < 128) v = st[rel * 2 * H + k] * Wself[((size_t)rel * H + k) * H + c];
        else         v = Wneigh[((size_t)rel * H + (k - 128)) * H + c];
        Wbt[idx] = f2b(v);
    } else if (threadIdx.x < H) {
        int rel = blockIdx.x - 384, c = threadIdx.x;
        const float* t = st + rel * 2 * H + H;
        float s = b[rel * H + c];
        for (int k = 0; k < H; k++) s += t[k] * Wself[((size_t)rel * H + k) * H + c];
        biasp[rel * H + c] = s;
    }
}

// ---------------- Final: mean + BN affine ----------------

__global__ void scale_out_kernel(float* __restrict__ out, const int* __restrict__ seg,
                                 const float* __restrict__ st_all) {
    int i = blockIdx.x * 256 + threadIdx.x;
    if (i >= N_GRAPHS * 3 * 4 * H) return;
    int g = i / (3 * 4 * H), k = i % (3 * 4 * H);
    int rel = k / (4 * H), rem = k % (4 * H), layer = rem / H, c = rem % H;
    const int* sg = seg + rel * N_NODES;
    int lo = 0, hi = N_NODES;
    while (lo < hi) { int m = (lo + hi) >> 1; if (sg[m] < g) lo = m + 1; else hi = m; }
    int start = lo;
    hi = N_NODES;
    while (lo < hi) { int m = (lo + hi) >> 1; if (sg[m] <= g) lo = m + 1; else hi = m; }
    int cnt = lo - start;
    float mean = out[i] / (float)max(cnt, 1);
    const float* st = st_all + ((size_t)layer * 3 + rel) * 2 * H;
    out[i] = st[c] * mean + st[H + c];
}

// ---------------- Orchestration ----------------

extern "C" void kernel_launch(void* const* d_in, const int* in_sizes, int n_in,
                              void* d_out, int out_size, void* d_ws, size_t ws_size,
                              hipStream_t stream) {
    const int* h_idx = (const int*)d_in[0];
    const int* p_idx = (const int*)d_in[1];
    const int* hp_idx = (const int*)d_in[2];
    const int* src = (const int*)d_in[3];
    const int* dst = (const int*)d_in[4];
    const int* seg = (const int*)d_in[5];
    const float* emb_h = (const float*)d_in[6];
    const float* emb_p = (const float*)d_in[7];
    const float* emb_hp = (const float*)d_in[8];
    const float* W1_self = (const float*)d_in[9];
    const float* W1_neigh = (const float*)d_in[10];
    const float* b1 = (const float*)d_in[11];
    const float* a1 = (const float*)d_in[12];
    const float* gamma1 = (const float*)d_in[13];
    const float* beta1 = (const float*)d_in[14];
    const float* W_self = (const float*)d_in[15];
    const float* W_neigh = (const float*)d_in[16];
    const float* b = (const float*)d_in[17];
    const float* a = (const float*)d_in[18];
    const float* gamma = (const float*)d_in[19];
    const float* beta = (const float*)d_in[20];
    float* out = (float*)d_out;

    // workspace
    char* p = (char*)d_ws;
    unsigned short* hpA = (unsigned short*)p; p += (size_t)3 * N_NODES * H * 2;    // 38.4 MB
    unsigned short* hpB = (unsigned short*)p; p += (size_t)3 * N_NODES * H * 2;    // 38.4 MB
    unsigned short* Wbt1 = (unsigned short*)p; p += (size_t)3 * H * 128 * 2;
    unsigned short* Wbt = (unsigned short*)p; p += (size_t)3 * H * 256 * 2;
    unsigned short* emb_bf = (unsigned short*)p; p += (size_t)3 * 257 * EMB * 2;
    float* biasp = (float*)p; p += 3 * H * sizeof(float);
    float* st_all = (float*)p; p += 4 * 3 * 2 * H * sizeof(float);
    float* stats = (float*)p; p += 3 * 256 * sizeof(float);
    int* deg = (int*)p; p += (size_t)3 * N_NODES * 4;
    int* row_ptr = (int*)p; p += (size_t)3 * (N_NODES + 1) * 4;
    int* cur = (int*)p; p += (size_t)3 * N_NODES * 4;
    int* gcur = (int*)p; p += (size_t)3 * NCH2 * 4;
    int* edge_src = (int*)p; p += (size_t)3 * N_EDGES * 4;
    unsigned long long* chunkbuf = (unsigned long long*)p; p += (size_t)3 * N_EDGES * 8;  // 9.6 MB

    hipMemsetAsync(out, 0, (size_t)N_GRAPHS * 3 * 4 * H * sizeof(float), stream);
    hipMemsetAsync(stats, 0, 3 * 256 * 4, stream);

    // CSR build: count -> scan(+chunk cursors) -> partition -> place -> sort
    hipMemsetAsync(deg, 0, (size_t)3 * N_NODES * 4, stream);
    dim3 eb((N_EDGES + 255) / 256, 3);
    count_deg_kernel<<<eb, 256, 0, stream>>>(dst, deg);
    scan_kernel<<<3, 1024, 0, stream>>>(deg, row_ptr, cur, gcur);
    partA_kernel<<<dim3(NSLA, 3), 256, 0, stream>>>(src, dst, gcur, chunkbuf);
    fillB_kernel<<<dim3(2 * NCH2, 3), 256, 0, stream>>>(row_ptr, chunkbuf, cur, edge_src);
    sort_adj_kernel<<<(3 * N_NODES + 255) / 256, 256, 0, stream>>>(row_ptr, edge_src);

    prep_init_kernel<<<217, 256, 0, stream>>>(W1_self, W1_neigh, Wbt1,
                                              emb_h, emb_p, emb_hp, emb_bf);

    dim3 gemm_grid((N_NODES + 127) / 128, 3);
    dim3 agg_grid((N_NODES + 95) / 96, 3);

    // ---- layer 1 (K = 64; nmean ld=64 in hpB via emb-table gather; out hpA) ----
    aggregate1_kernel<<<dim3((N_NODES + 31) / 32, 3), 256, 0, stream>>>(
        h_idx, p_idx, hp_idx, emb_bf, row_ptr, edge_src, hpB);
    gemm_kernel<64, true, true><<<gemm_grid, 256, 0, stream>>>(
        emb_bf /*unused*/, hpB, Wbt1, b1, a1, hpA, stats, seg, out, 0,
        emb_bf, h_idx, p_idx, hp_idx);
    finalize_kernel<<<3, H, 0, stream>>>(stats, gamma1, beta1, st_all);

    // ---- layers 2-4 (K = 128; out aliases nmean; last layer skips hp store) ----
    unsigned short* xin = hpA;
    unsigned short* xout = hpB;
    for (int l = 0; l < 3; l++) {
        const float* st_prev = st_all + (size_t)l * 3 * 2 * H;
        prep_kernel<<<387, 256, 0, stream>>>(
            W_self + (size_t)l * 3 * H * H, W_neigh + (size_t)l * 3 * H * H,
            b + (size_t)l * 3 * H, st_prev, Wbt, biasp);
        aggregate_kernel<true><<<agg_grid, 256, 0, stream>>>(
            xin, row_ptr, edge_src, st_prev, xout);
        if (l < 2)
            gemm_kernel<128, false, true><<<gemm_grid, 256, 0, stream>>>(
                xin, xout, Wbt, biasp, a + (size_t)l * 3 * H, xout, stats, seg, out, l + 1,
                nullptr, nullptr, nullptr, nullptr);
        else
            gemm_kernel<128, false, false><<<gemm_grid, 256, 0, stream>>>(
                xin, xout, Wbt, biasp, a + (size_t)l * 3 * H, xout, stats, seg, out, l + 1,
                nullptr, nullptr, nullptr, nullptr);
        finalize_kernel<<<3, H, 0, stream>>>(
            stats, gamma + (size_t)l * 3 * H, beta + (size_t)l * 3 * H,
            st_all + (size_t)(l + 1) * 3 * 2 * H);
        unsigned short* t = xin; xin = xout; xout = t;
    }

    scale_out_kernel<<<(N_GRAPHS * 3 * 4 * H + 255) / 256, 256, 0, stream>>>(out, seg, st_all);
}